// Round 20
// baseline (419.899 us; speedup 1.0000x reference)
//
#include <hip/hip_runtime.h>

#define BB 8
#define CP 21
#define CF 22
#define CLOW 3
#define CHIGH 256
#define WW 80
#define VV 6400
#define EVERT 6320
#define EE 12640
#define TT 16
#define SIGMA_F 0.002f
#define ROOT 3240          // seed vertex for tour break / diameter search

#define NE (VV - 1)        // tree edges
#define NA (2 * NE)        // Euler arcs = 12798
#define NILA 0xFFFFu
#define NB 200             // ceil(NA/64) RMQ blocks

__device__ __forceinline__ void edge_uv(int e, int& u, int& v) {
  if (e < EVERT) { u = e; v = e + WW; }
  else { int e2 = e - EVERT; int r = e2 / (WW - 1); int c = e2 - r * (WW - 1); u = r * WW + c; v = u + 1; }
}

// ---------------- K1: softmax over 21 channels, per pixel ----------------
__global__ void k_softmax(const float* __restrict__ preds, float* __restrict__ prob) {
  int i = blockIdx.x * blockDim.x + threadIdx.x;
  if (i >= BB * VV) return;
  int b = i / VV, v = i - b * VV;
  const float* p = preds + (size_t)b * CP * VV + v;
  float m = -1e30f;
  #pragma unroll
  for (int c = 0; c < CP; c++) m = fmaxf(m, p[c * VV]);
  float e[CP], s = 0.f;
  #pragma unroll
  for (int c = 0; c < CP; c++) { float x = expf(p[c * VV] - m); e[c] = x; s += x; }
  float inv = 1.f / s;
  float* o = prob + (size_t)b * CP * VV + v;
  #pragma unroll
  for (int c = 0; c < CP; c++) o[c * VV] = e[c] * inv;
}

// ---------------- K2: edge keys (float64 cost, top-50-bits | edge idx) ----------------
__global__ void k_edgekey(const float* __restrict__ low, const float* __restrict__ high,
                          unsigned long long* __restrict__ ekey) {
  int i = blockIdx.x * blockDim.x + threadIdx.x;
  if (i >= TT * EE) return;
  int t = i / EE, e = i - t * EE;
  int u, v; edge_uv(e, u, v);
  double acc = 0.0;
  if (t < BB) {
    const float* emb = low + (size_t)t * CLOW * VV;
    for (int c = 0; c < CLOW; c++) { double d = (double)emb[c * VV + u] - (double)emb[c * VV + v]; acc += d * d; }
  } else {
    const float* emb = high + (size_t)(t - BB) * CHIGH * VV;
    for (int c = 0; c < CHIGH; c++) { double d = (double)emb[c * VV + u] - (double)emb[c * VV + v]; acc += d * d; }
  }
  unsigned long long bits = (unsigned long long)__double_as_longlong(acc);
  ekey[i] = (bits & ~0x3FFFULL) | (unsigned long long)e;
}

// ---------------- K3: parallel Boruvka MST, edge compaction + barrier-free compression ----------------
__global__ __launch_bounds__(1024) void k_boruvka(const unsigned long long* __restrict__ ekey,
    int* __restrict__ mstU, int* __restrict__ mstV) {
  int t = blockIdx.x;
  const unsigned long long* key = ekey + (size_t)t * EE;
  int* mu = mstU + t * VV;
  int* mv = mstV + t * VV;
  __shared__ int comp[VV];
  __shared__ unsigned long long bst[VV];
  __shared__ unsigned short tgtS[VV];
  __shared__ unsigned short el0[EE];
  __shared__ unsigned short el1[EE];
  __shared__ int changed, cnt, necnt;
  int tid = threadIdx.x;
  const int nt = 1024;
  for (int v = tid; v < VV; v += nt) comp[v] = v;
  for (int e = tid; e < EE; e += nt) el0[e] = (unsigned short)e;
  if (tid == 0) cnt = 0;
  __syncthreads();
  unsigned short* els = el0;
  unsigned short* eld = el1;
  int ecnt = EE;
  for (int round = 0; round < 48 && ecnt > 0; round++) {
    for (int v = tid; v < VV; v += nt) bst[v] = ~0ULL;
    if (tid == 0) { changed = 0; necnt = 0; }
    __syncthreads();
    for (int j = tid; j < ecnt; j += nt) {
      int e = els[j];
      int u, v; edge_uv(e, u, v);
      int cu = comp[u], cv = comp[v];
      if (cu != cv) { unsigned long long k = key[e]; atomicMin(&bst[cu], k); atomicMin(&bst[cv], k); }
    }
    __syncthreads();
    for (int c = tid; c < VV; c += nt) {
      unsigned short tg = (unsigned short)NILA;
      if (comp[c] == c) {
        unsigned long long k = bst[c];
        if (k != ~0ULL) {
          int e = (int)(k & 0x3FFFULL);
          int u, v; edge_uv(e, u, v);
          int cu = comp[u], cv = comp[v];
          tg = (unsigned short)((cu == c) ? cv : cu);
        }
      }
      tgtS[c] = tg;
    }
    __syncthreads();
    for (int c = tid; c < VV; c += nt) {
      int o = tgtS[c];
      if (o == (int)NILA) continue;
      unsigned long long k = bst[c];
      if (bst[o] == k && c < o) continue;  // mutual minimum edge: smaller id stays root
      comp[c] = o;
      int slot = atomicAdd(&cnt, 1);
      int e = (int)(k & 0x3FFFULL);
      int u, v; edge_uv(e, u, v);
      mu[slot] = u; mv[slot] = v;
      changed = 1;
    }
    __syncthreads();
    if (!changed) break;
    // barrier-free full path compression
    for (int v = tid; v < VV; v += nt) {
      int c = comp[v];
      int c2 = comp[c];
      if (c2 != c) {
        int r0 = c2;
        while (true) { int n = comp[r0]; if (n == r0) break; r0 = n; }
        comp[v] = r0;
      }
    }
    __syncthreads();
    for (int j = tid; j < ecnt; j += nt) {
      int e = els[j];
      int u, v; edge_uv(e, u, v);
      if (comp[u] != comp[v]) { int s = atomicAdd(&necnt, 1); eld[s] = (unsigned short)e; }
    }
    __syncthreads();
    ecnt = necnt;
    __syncthreads();
    unsigned short* tp = els; els = eld; eld = tp;
  }
}

// ---------------- K4: Euler-tour rooting at TRUE TREE CENTER + child-grouped layout ----------------
// Round-18 machinery (packed ranking, shfl scans, O(1) RMQ center) + Phase D':
// positions assigned via per-parent contiguous child spans -> csG=(cnt<<13)|childStart.
__global__ __launch_bounds__(1024) void k_buildtree(const int* __restrict__ mstU, const int* __restrict__ mstV,
    int* __restrict__ ordG, int* __restrict__ spG, int* __restrict__ pvG,
    int* __restrict__ lpG, unsigned short* __restrict__ csG, int* __restrict__ nlevG) {
  int t = blockIdx.x;
  const int* mu = mstU + t * VV;
  const int* mv = mstV + t * VV;
  int tid = threadIdx.x;
  const int nt = 1024;
  int lane = tid & 63, wid = tid >> 6;

  __shared__ int buf4[32004];
  char* buf = (char*)buf4;
  __shared__ int part[64];
  __shared__ short tbl[8 * NB];
  __shared__ unsigned short dbuf2[VV];
  __shared__ int lasts, spackU, spackW, scenter, smaxd;

  int* deg = (int*)(buf + 0);
  int* off = (int*)(buf + 25600);
  unsigned short* adjA = (unsigned short*)(buf + 51208);
  unsigned short* succ = (unsigned short*)(buf + 102408);
  int* pk0 = (int*)(buf + 0);
  int* pk1 = (int*)(buf + 51208);
  unsigned short* r_a = (unsigned short*)(buf + 102408);
  short* H = (short*)(buf + 51208);
  unsigned short* depthR = (unsigned short*)(buf + 76808);
  unsigned short* firstK = (unsigned short*)(buf + 89608);
  short* prefmin = (short*)(buf + 0);
  short* sufmin  = (short*)(buf + 25600);
  unsigned short* distU = (unsigned short*)(buf + 76808);
  unsigned short* parentS = (unsigned short*)(buf + 76808);
  // Phase D' regions (liveness: all prior occupants dead at that point)
  int* lvA = (int*)(buf + 0);                         // lev histogram, then per-parent cursors
  int* curB = (int*)(buf + 25604);                    // level cursors
  int* cntC = (int*)(buf + 51208);                    // childCnt per vertex (H dead)
  unsigned short* spanS = (unsigned short*)(buf + 89608);  // child span per vertex (firstK dead)
  unsigned short* ordS = (unsigned short*)(buf + 102408);  // r_a dead after parents pass
  unsigned short* posS = (unsigned short*)(buf + 115208);

  auto blockScanEx = [&](int s) -> int {
    int x = s;
    #pragma unroll
    for (int d = 1; d < 64; d <<= 1) { int o = __shfl_up(x, d); if (lane >= d) x += o; }
    if (lane == 63) part[wid] = x;
    __syncthreads();
    if (wid == 0) {
      int y = (lane < 16) ? part[lane] : 0;
      #pragma unroll
      for (int d = 1; d < 16; d <<= 1) { int o = __shfl_up(y, d); if (lane >= d) y += o; }
      if (lane < 16) part[lane] = y;
    }
    __syncthreads();
    int base = (wid > 0) ? part[wid - 1] : 0;
    return base + (x - s);
  };

  // ---- Phase A: CSR + Euler successors ----
  for (int v = tid; v < VV; v += nt) deg[v] = 0;
  __syncthreads();
  for (int e = tid; e < NE; e += nt) { atomicAdd(&deg[mu[e]], 1); atomicAdd(&deg[mv[e]], 1); }
  __syncthreads();
  {
    const int SCH = 7;
    int base = tid * SCH;
    int s = 0;
    #pragma unroll
    for (int k = 0; k < SCH; k++) { int v = base + k; if (v < VV) s += deg[v]; }
    int ex = blockScanEx(s);
    #pragma unroll
    for (int k = 0; k < SCH; k++) { int v = base + k; if (v < VV) { off[v] = ex; ex += deg[v]; } }
    if (tid == 1023) off[VV] = ex;
  }
  __syncthreads();
  for (int v = tid; v < VV; v += nt) deg[v] = off[v];
  __syncthreads();
  for (int e = tid; e < NE; e += nt) {
    int u = mu[e], v = mv[e];
    adjA[atomicAdd(&deg[u], 1)] = (unsigned short)(2 * e);
    adjA[atomicAdd(&deg[v], 1)] = (unsigned short)(2 * e + 1);
  }
  __syncthreads();
  for (int v = tid; v < VV; v += nt) {
    int b0 = off[v], dv = off[v + 1] - b0;
    for (int k = 0; k < dv; k++) {
      unsigned short a = adjA[b0 + k];
      unsigned short b = adjA[b0 + ((k + 1 == dv) ? 0 : k + 1)];
      succ[a ^ 1] = b;
    }
  }
  if (tid == 0) lasts = adjA[off[ROOT] + (off[ROOT + 1] - off[ROOT]) - 1] ^ 1;
  __syncthreads();
  if (tid == 0) succ[lasts] = (unsigned short)NILA;
  __syncthreads();
  // ---- Phase B: packed list ranking ----
  for (int a = tid; a < NA; a += nt) {
    unsigned int n = succ[a];
    pk0[a] = ((n == NILA ? 0 : 1) << 16) | (int)n;
  }
  __syncthreads();
  {
    int* px = pk0;
    int* py = pk1;
    for (int rd = 0; rd < 14; rd++) {
      for (int a = tid; a < NA; a += nt) {
        int cur_ = px[a];
        int n = cur_ & 0xFFFF;
        if (n != (int)NILA) {
          int o = px[n];
          cur_ = (((cur_ >> 16) + (o >> 16)) << 16) | (o & 0xFFFF);
        }
        py[a] = cur_;
      }
      __syncthreads();
      int* tp = px; px = py; py = tp;
    }
    for (int a = tid; a < NA; a += nt) r_a[a] = (unsigned short)(pk0[a] >> 16);
  }
  __syncthreads();
  // ---- tour values + shfl scan -> H ----
  for (int a = tid; a < NA; a += nt) {
    int pa = NA - 1 - (int)r_a[a];
    int pb = NA - 1 - (int)r_a[a ^ 1];
    H[pa] = (pa < pb) ? (short)1 : (short)-1;
  }
  __syncthreads();
  {
    const int SCH = 13;
    int base = tid * SCH;
    int lim = base + SCH; if (lim > NA) lim = NA;
    int s = 0;
    for (int j = base; j < lim; j++) s += H[j];
    int run = blockScanEx(s);
    for (int j = base; j < lim; j++) { run += H[j]; H[j] = (short)run; }
  }
  __syncthreads();
  if (tid == 0) { spackU = 0; smaxd = 0; scenter = 0x7FFFFFFF; }
  __syncthreads();
  for (int a = tid; a < NA; a += nt) {
    int pa = NA - 1 - (int)r_a[a];
    int pb = NA - 1 - (int)r_a[a ^ 1];
    if (pa < pb) {
      int e = a >> 1;
      int head = (a & 1) ? mu[e] : mv[e];
      depthR[head] = (unsigned short)H[pa];
      firstK[head] = (unsigned short)(pa + 1);
    }
  }
  if (tid == 0) { depthR[ROOT] = 0; firstK[ROOT] = 0; }
  __syncthreads();
  {
    int loc = 0;
    for (int v = tid; v < VV; v += nt) { int p = ((int)depthR[v] << 13) | v; if (p > loc) loc = p; }
    #pragma unroll
    for (int d = 32; d > 0; d >>= 1) { int o = __shfl_down(loc, d); if (o > loc) loc = o; }
    if (lane == 0) atomicMax(&spackU, loc);
  }
  __syncthreads();
  // ---- RMQ build: wave-parallel segmented min-scan ----
  {
    for (int seg = wid; seg < NB; seg += 16) {
      int p = seg * 64 + lane;
      int h = (p < NA) ? (int)H[p] : 32767;
      int hp = h;
      #pragma unroll
      for (int d = 1; d < 64; d <<= 1) { int o = __shfl_up(hp, d); if (lane >= d && o < hp) hp = o; }
      prefmin[p] = (short)hp;
      int hs = h;
      #pragma unroll
      for (int d = 1; d < 64; d <<= 1) { int o = __shfl_down(hs, d); if (lane + d < 64 && o < hs) hs = o; }
      sufmin[p] = (short)hs;
      if (lane == 0) tbl[seg] = (short)hs;
    }
  }
  __syncthreads();
  for (int k = 1; k < 8; k++) {
    short vv_ = 0;
    if (tid < NB) {
      int o = tid + (1 << (k - 1));
      short a = tbl[(k - 1) * NB + tid];
      short b2 = (o < NB) ? tbl[(k - 1) * NB + o] : (short)32767;
      vv_ = (a < b2) ? a : b2;
    }
    __syncthreads();
    if (tid < NB) tbl[k * NB + tid] = vv_;
    __syncthreads();
  }
  auto distq = [&](int K1, int K2) -> int {
    if (K1 == K2) return 0;
    int l = (K1 < K2 ? K1 : K2) - 1;
    int r = (K1 > K2 ? K1 : K2) - 1;
    int m = 32767;
    int l0 = l < 0 ? 0 : l;
    int bl = l0 >> 6, br = r >> 6;
    if (bl == br) {
      for (int p = l0; p <= r; p++) { int h = H[p]; if (h < m) m = h; }
    } else {
      int a = sufmin[l0], b2 = prefmin[r];
      m = a < b2 ? a : b2;
      int lo = bl + 1, hi = br - 1;
      if (lo <= hi) {
        int L = hi - lo + 1;
        int k = 31 - __builtin_clz(L);
        int c1 = tbl[k * NB + lo];
        int c2 = tbl[k * NB + hi - (1 << k) + 1];
        if (c1 < m) m = c1;
        if (c2 < m) m = c2;
      }
    }
    if (l < 0 && 0 < m) m = 0;
    int h1 = (K1 == 0) ? 0 : (int)H[K1 - 1];
    int h2 = (K2 == 0) ? 0 : (int)H[K2 - 1];
    return h1 + h2 - 2 * m;
  };
  int u = spackU & 0x1FFF;
  int Ku = firstK[u];
  if (tid == 0) spackW = 0;
  __syncthreads();
  {
    int loc = 0;
    for (int v = tid; v < VV; v += nt) {
      int d = distq(Ku, firstK[v]);
      distU[v] = (unsigned short)d;
      int p = (d << 13) | v;
      if (p > loc) loc = p;
    }
    #pragma unroll
    for (int d = 32; d > 0; d >>= 1) { int o = __shfl_down(loc, d); if (o > loc) loc = o; }
    if (lane == 0) atomicMax(&spackW, loc);
  }
  __syncthreads();
  int D = spackW >> 13;
  int w = spackW & 0x1FFF;
  int Kw = firstK[w];
  for (int v = tid; v < VV; v += nt) dbuf2[v] = (unsigned short)distq(Kw, firstK[v]);
  __syncthreads();
  {
    int half = D >> 1;
    for (int v = tid; v < VV; v += nt) {
      if ((int)distU[v] == half && (int)distU[v] + (int)dbuf2[v] == D) atomicMin(&scenter, v);
    }
  }
  __syncthreads();
  int cvert = (scenter == 0x7FFFFFFF) ? ROOT : scenter;
  int Kc = firstK[cvert];
  __syncthreads();
  {
    int loc = 0;
    for (int v = tid; v < VV; v += nt) {
      int d = distq(Kc, firstK[v]);
      dbuf2[v] = (unsigned short)d;
      if (d > loc) loc = d;
    }
    #pragma unroll
    for (int d = 32; d > 0; d >>= 1) { int o = __shfl_down(loc, d); if (o > loc) loc = o; }
    if (lane == 0) atomicMax(&smaxd, loc);
  }
  __syncthreads();
  int maxd = smaxd;
  int sTil = Kc;
  // ---- parents under c: one rotated arc-pass (uses r_a; r_a dead after) ----
  for (int a = tid; a < NA; a += nt) {
    int pa = NA - 1 - (int)r_a[a];
    int pb = NA - 1 - (int)r_a[a ^ 1];
    int pa2 = pa - sTil; if (pa2 < 0) pa2 += NA;
    int pb2 = pb - sTil; if (pb2 < 0) pb2 += NA;
    if (pa2 < pb2) {
      int e = a >> 1;
      int head = (a & 1) ? mu[e] : mv[e];
      int tail = (a & 1) ? mv[e] : mu[e];
      parentS[head] = (unsigned short)tail;
    }
  }
  if (tid == 0) parentS[cvert] = (unsigned short)cvert;
  __syncthreads();
  // ---- Phase D': child-grouped level layout ----
  for (int d = tid; d <= VV; d += nt) lvA[d] = 0;
  for (int v = tid; v < VV; v += nt) cntC[v] = 0;
  __syncthreads();
  for (int v = tid; v < VV; v += nt) {
    atomicAdd(&lvA[dbuf2[v]], 1);
    if (v != cvert) atomicAdd(&cntC[parentS[v]], 1);
  }
  __syncthreads();
  {
    const int SCH = 7;
    int base = tid * SCH;
    int s = 0;
    #pragma unroll
    for (int k = 0; k < SCH; k++) { int d = base + k; if (d <= VV) s += lvA[d]; }
    int ex = blockScanEx(s);
    #pragma unroll
    for (int k = 0; k < SCH; k++) {
      int d = base + k;
      if (d <= VV) {
        int st = ex;
        ex += lvA[d];
        if (d < VV) curB[d] = st;
        lpG[t * (VV + 1) + d] = st;
      }
    }
  }
  __syncthreads();
  // span allocation per parent (children live at level dist+1)
  for (int v = tid; v < VV; v += nt) {
    int cc = cntC[v];
    if (cc > 0) spanS[v] = (unsigned short)atomicAdd(&curB[(int)dbuf2[v] + 1], cc);
  }
  __syncthreads();
  for (int v = tid; v < VV; v += nt) lvA[v] = 0;   // per-parent cursors
  __syncthreads();
  for (int v = tid; v < VV; v += nt) {
    if (v != cvert) {
      int p = parentS[v];
      int pos = spanS[p] + atomicAdd(&lvA[p], 1);
      posS[v] = (unsigned short)pos;
      ordS[pos] = (unsigned short)v;
    }
  }
  if (tid == 0) { posS[cvert] = 0; ordS[0] = (unsigned short)cvert; }
  __syncthreads();
  for (int j = tid; j < VV; j += nt) {
    int v = ordS[j];
    int pv = parentS[v];
    ordG[t * VV + j] = v;
    pvG[t * VV + j] = pv;
    spG[t * VV + j] = posS[pv];
    int cc = cntC[v];
    csG[t * VV + j] = (unsigned short)((cc << 13) | (cc ? (int)spanS[v] : 0));
  }
  if (tid == 0) nlevG[t] = maxd + 1;
}

// ---------------- K5: per-position weight to parent (edge-key reuse; root -> 0) ----------------
__global__ void k_weights(const unsigned long long* __restrict__ ekey,
                          const int* __restrict__ ordG, const int* __restrict__ pvG,
                          float* __restrict__ wvp) {
  int i = blockIdx.x * blockDim.x + threadIdx.x;
  if (i >= TT * VV) return;
  int t = i / VV;
  int v = ordG[i], p = pvG[i];
  float wout;
  if (v == p) {
    wout = 0.0f;  // root: chain terminator / transform no-op
  } else {
    int a = v < p ? v : p;
    int diff = v < p ? p - v : v - p;
    int e;
    if (diff == WW) e = a;
    else { int r = a / WW, c = a - r * WW; e = EVERT + r * (WW - 1) + c; }
    unsigned long long k = ekey[(size_t)t * EE + e];
    double cost = __longlong_as_double((long long)(k & ~0x3FFFULL));
    wout = expf(-(float)cost / SIGMA_F);
  }
  wvp[i] = wout;
}

// ---------------- K6: tree filter — pull-based chains (no atomics, no doubling) ----------------
// Up: S_j = f_j + sum over contiguous children (w_c*S_c).  Down: A_j = b_j + w_j*A_parent, in place.
__global__ __launch_bounds__(512) void k_filter_pc(const float* __restrict__ Fsrc, float* __restrict__ Araw,
    const float* __restrict__ wvp, const int* __restrict__ ordG, const int* __restrict__ spG,
    const unsigned short* __restrict__ csG,
    const int* __restrict__ lpG, const int* __restrict__ nlevG, int treeBase) {
  int blk = blockIdx.x;
  int b = blk / CF, ch = blk - b * CF;
  int t = treeBase + b;
  // Arena: w f32 @0 | s f32 @25600 | sp0 u16 @51200 | cspk u16 @64000 | lpS u16 @76800
  __shared__ alignas(16) char arena[89608];
  float* w   = (float*)(arena);
  float* s   = (float*)(arena + 25600);
  unsigned short* sp0  = (unsigned short*)(arena + 51200);
  unsigned short* cspk = (unsigned short*)(arena + 64000);
  unsigned short* lpS  = (unsigned short*)(arena + 76800);   // u16[VV+1]
  const int* ord = ordG + t * VV;
  const int* spt = spG + t * VV;
  const unsigned short* cst = csG + (size_t)t * VV;
  const float* wsrc = wvp + t * VV;
  const int* lp = lpG + t * (VV + 1);
  int tid = threadIdx.x;
  const int nt = 512;
  int NL = nlevG[t];
  for (int j = tid; j <= NL; j += nt) lpS[j] = (unsigned short)lp[j];
  const bool norm_in = (treeBase != 0);
  for (int j = tid; j < VV; j += nt) {
    sp0[j] = (unsigned short)spt[j];
    cspk[j] = cst[j];
    w[j] = wsrc[j];            // 0 at root (position 0)
    float val;
    if (ch < CP) {
      int v = ord[j];
      if (!norm_in) val = Fsrc[((size_t)b * CP + ch) * VV + v];
      else          val = Fsrc[((size_t)b * CF + ch) * VV + v] / Fsrc[((size_t)b * CF + CP) * VV + v];
    } else val = 1.0f;
    s[j] = val;
  }
  __syncthreads();
  // ---- up-sweep: pull from contiguous children, wave 0, plain writes ----
  if (tid < 64) {
    for (int l = NL - 2; l >= 0; l--) {
      int s0 = lpS[l], s1 = lpS[l + 1];
      for (int j = s0 + tid; j < s1; j += 64) {
        unsigned short pk = cspk[j];
        int cn = pk >> 13;
        int c0 = pk & 0x1FFF;
        float acc = s[j];
        for (int k = 0; k < cn; k++) acc += w[c0 + k] * s[c0 + k];
        s[j] = acc;
      }
      asm volatile("s_waitcnt lgkmcnt(0)" ::: "memory");
      __builtin_amdgcn_sched_barrier(0);
    }
  }
  __syncthreads();
  // ---- transform: b_j = S_j*(1-w_j^2) in place (root w=0 -> b=S=A_root) ----
  for (int j = tid; j < VV; j += nt) {
    float wv = w[j];
    s[j] *= (1.f - wv * wv);
  }
  __syncthreads();
  // ---- down-sweep: pull from parent, wave 0, in place ----
  if (tid < 64) {
    for (int l = 1; l < NL; l++) {
      int s0 = lpS[l], s1 = lpS[l + 1];
      for (int j = s0 + tid; j < s1; j += 64) {
        s[j] = fmaf(w[j], s[sp0[j]], s[j]);
      }
      asm volatile("s_waitcnt lgkmcnt(0)" ::: "memory");
      __builtin_amdgcn_sched_barrier(0);
    }
  }
  __syncthreads();
  // ---- scatter to vertex space ----
  float* Ob = Araw + ((size_t)b * CF + ch) * VV;
  for (int j = tid; j < VV; j += nt) Ob[ord[j]] = s[j];
}

// ---------------- K7: ROI-masked L1 loss (fused normalize of stage 2) ----------------
__global__ void k_loss(const float* __restrict__ prob, const float* __restrict__ Araw2,
                       const int* __restrict__ roi, double* __restrict__ acc) {
  int i = blockIdx.x * blockDim.x + threadIdx.x;
  int tid = threadIdx.x;
  double s = 0.0, n = 0.0;
  if (i < BB * VV) {
    int b = i / VV, v = i - b * VV;
    if (roi[i] != 0) {
      n = 1.0;
      const float* pb = prob + (size_t)b * CP * VV + v;
      const float* ab = Araw2 + (size_t)b * CF * VV + v;
      float inv = 1.0f / ab[CP * VV];
      float ls = 0.f;
      #pragma unroll
      for (int c = 0; c < CP; c++) ls += fabsf(pb[c * VV] - ab[c * VV] * inv);
      s = (double)ls;
    }
  }
  __shared__ double rs[256], rn[256];
  rs[tid] = s; rn[tid] = n;
  __syncthreads();
  for (int d = 128; d > 0; d >>= 1) {
    if (tid < d) { rs[tid] += rs[tid + d]; rn[tid] += rn[tid + d]; }
    __syncthreads();
  }
  if (tid == 0) { atomicAdd(&acc[0], rs[0]); atomicAdd(&acc[1], rn[0]); }
}

__global__ void k_finalize(const double* __restrict__ acc, float* __restrict__ out) {
  out[0] = (acc[1] > 0.0) ? (float)(acc[0] / acc[1]) : 0.0f;
}

extern "C" void kernel_launch(void* const* d_in, const int* in_sizes, int n_in,
                              void* d_out, int out_size, void* d_ws, size_t ws_size,
                              hipStream_t stream) {
  const float* preds = (const float*)d_in[0];
  const float* low   = (const float*)d_in[1];
  const float* high  = (const float*)d_in[2];
  const int*   roi   = (const int*)d_in[3];
  float* out = (float*)d_out;

  char* w = (char*)d_ws;
  size_t off = 0;
  auto alloc = [&](size_t bytes) -> void* {
    void* p = w + off;
    off += (bytes + 255) & ~(size_t)255;
    return p;
  };
  float* prob  = (float*)alloc((size_t)BB * CP * VV * 4);
  float* Araw1 = (float*)alloc((size_t)BB * CF * VV * 4);
  float* Araw2 = (float*)alloc((size_t)BB * CF * VV * 4);
  unsigned long long* ekey = (unsigned long long*)alloc((size_t)TT * EE * 8);
  int* mstU = (int*)alloc((size_t)TT * VV * 4);
  int* mstV = (int*)alloc((size_t)TT * VV * 4);
  int* ordG = (int*)alloc((size_t)TT * VV * 4);
  int* spG  = (int*)alloc((size_t)TT * VV * 4);
  int* pvG  = (int*)alloc((size_t)TT * VV * 4);
  int* lpG  = (int*)alloc((size_t)TT * (VV + 1) * 4);
  unsigned short* csG = (unsigned short*)alloc((size_t)TT * VV * 2);
  int* nlev = (int*)alloc((size_t)TT * 4);
  float* wvp = (float*)alloc((size_t)TT * VV * 4);
  double* acc = (double*)alloc(16);

  hipMemsetAsync(acc, 0, 16, stream);

  k_softmax<<<(BB * VV + 255) / 256, 256, 0, stream>>>(preds, prob);
  k_edgekey<<<(TT * EE + 255) / 256, 256, 0, stream>>>(low, high, ekey);
  k_boruvka<<<TT, 1024, 0, stream>>>(ekey, mstU, mstV);
  k_buildtree<<<TT, 1024, 0, stream>>>(mstU, mstV, ordG, spG, pvG, lpG, csG, nlev);
  k_weights<<<(TT * VV + 255) / 256, 256, 0, stream>>>(ekey, ordG, pvG, wvp);
  k_filter_pc<<<BB * CF, 512, 0, stream>>>(prob,  Araw1, wvp, ordG, spG, csG, lpG, nlev, 0);
  k_filter_pc<<<BB * CF, 512, 0, stream>>>(Araw1, Araw2, wvp, ordG, spG, csG, lpG, nlev, BB);
  k_loss<<<(BB * VV + 255) / 256, 256, 0, stream>>>(prob, Araw2, roi, acc);
  k_finalize<<<1, 1, 0, stream>>>(acc, out);
}

// Round 21
// 301.065 us; speedup vs baseline: 1.3947x; 1.3947x over previous
//
#include <hip/hip_runtime.h>

#define BB 8
#define CP 21
#define CF 22
#define CLOW 3
#define CHIGH 256
#define WW 80
#define VV 6400
#define EVERT 6320
#define EE 12640
#define TT 16
#define SIGMA_F 0.002f
#define ROOT 3240          // seed vertex for tour break / diameter search

#define NE (VV - 1)        // tree edges
#define NA (2 * NE)        // Euler arcs = 12798
#define NILA 0xFFFFu
#define NB 200             // ceil(NA/64) RMQ blocks

__device__ __forceinline__ void edge_uv(int e, int& u, int& v) {
  if (e < EVERT) { u = e; v = e + WW; }
  else { int e2 = e - EVERT; int r = e2 / (WW - 1); int c = e2 - r * (WW - 1); u = r * WW + c; v = u + 1; }
}

// ---------------- K1: softmax over 21 channels, per pixel ----------------
__global__ void k_softmax(const float* __restrict__ preds, float* __restrict__ prob) {
  int i = blockIdx.x * blockDim.x + threadIdx.x;
  if (i >= BB * VV) return;
  int b = i / VV, v = i - b * VV;
  const float* p = preds + (size_t)b * CP * VV + v;
  float m = -1e30f;
  #pragma unroll
  for (int c = 0; c < CP; c++) m = fmaxf(m, p[c * VV]);
  float e[CP], s = 0.f;
  #pragma unroll
  for (int c = 0; c < CP; c++) { float x = expf(p[c * VV] - m); e[c] = x; s += x; }
  float inv = 1.f / s;
  float* o = prob + (size_t)b * CP * VV + v;
  #pragma unroll
  for (int c = 0; c < CP; c++) o[c * VV] = e[c] * inv;
}

// ---------------- K2: edge keys (float64 cost, top-50-bits | edge idx) ----------------
__global__ void k_edgekey(const float* __restrict__ low, const float* __restrict__ high,
                          unsigned long long* __restrict__ ekey) {
  int i = blockIdx.x * blockDim.x + threadIdx.x;
  if (i >= TT * EE) return;
  int t = i / EE, e = i - t * EE;
  int u, v; edge_uv(e, u, v);
  double acc = 0.0;
  if (t < BB) {
    const float* emb = low + (size_t)t * CLOW * VV;
    for (int c = 0; c < CLOW; c++) { double d = (double)emb[c * VV + u] - (double)emb[c * VV + v]; acc += d * d; }
  } else {
    const float* emb = high + (size_t)(t - BB) * CHIGH * VV;
    for (int c = 0; c < CHIGH; c++) { double d = (double)emb[c * VV + u] - (double)emb[c * VV + v]; acc += d * d; }
  }
  unsigned long long bits = (unsigned long long)__double_as_longlong(acc);
  ekey[i] = (bits & ~0x3FFFULL) | (unsigned long long)e;
}

// ---------------- K3: FUSED per-tree: Boruvka MST + Euler center rooting + weights ----------------
__global__ __launch_bounds__(1024) void k_msttree(const unsigned long long* __restrict__ ekey,
    int* __restrict__ mstU, int* __restrict__ mstV,
    int* __restrict__ ordG, int* __restrict__ spG,
    int* __restrict__ lpG, int* __restrict__ nlevG, float* __restrict__ wvp) {
  int t = blockIdx.x;
  const unsigned long long* key = ekey + (size_t)t * EE;
  int* mu = mstU + t * VV;
  int* mv = mstV + t * VV;
  int tid = threadIdx.x;
  const int nt = 1024;
  int lane = tid & 63, wid = tid >> 6;

  __shared__ alignas(16) char arena[144384];
  __shared__ int lasts, spackU, spackW, scenter, smaxd, changed, cnt, necnt;

  // ===== Phase 1 regions (Boruvka) =====
  int* comp = (int*)(arena + 0);                            // int[VV]
  unsigned long long* bst = (unsigned long long*)(arena + 25600);  // u64[VV]
  unsigned short* tgtS = (unsigned short*)(arena + 76800);  // u16[VV]
  unsigned short* el0 = (unsigned short*)(arena + 89600);   // u16[EE]
  unsigned short* el1 = (unsigned short*)(arena + 114880);  // u16[EE] -> ends 140160

  // ===== Phase 2 regions (Euler rooting; overlays Phase 1) =====
  char* buf = arena;
  int* deg = (int*)(buf + 0);
  int* off = (int*)(buf + 25600);
  unsigned short* adjA = (unsigned short*)(buf + 51208);
  unsigned short* succ = (unsigned short*)(buf + 102408);
  int* pk0 = (int*)(buf + 0);
  int* pk1 = (int*)(buf + 51208);
  unsigned short* r_a = (unsigned short*)(buf + 102408);
  short* H = (short*)(buf + 51208);
  unsigned short* depthR = (unsigned short*)(buf + 76808);
  unsigned short* firstK = (unsigned short*)(buf + 89608);
  short* prefmin = (short*)(buf + 0);
  short* sufmin  = (short*)(buf + 25600);
  unsigned short* distU = (unsigned short*)(buf + 76808);
  unsigned short* parentS = (unsigned short*)(buf + 76808);
  int* lev = (int*)(buf + 0);
  int* cur = (int*)(buf + 25604);
  unsigned short* ordS = (unsigned short*)(buf + 51208);
  unsigned short* posS = (unsigned short*)(buf + 64008);
  int* part = (int*)(buf + 128016);                         // int[64]
  short* tbl = (short*)(buf + 128272);                      // short[8*NB]
  unsigned short* dbuf2 = (unsigned short*)(buf + 131472);  // u16[VV] -> ends 144272

  auto blockScanEx = [&](int s) -> int {
    int x = s;
    #pragma unroll
    for (int d = 1; d < 64; d <<= 1) { int o = __shfl_up(x, d); if (lane >= d) x += o; }
    if (lane == 63) part[wid] = x;
    __syncthreads();
    if (wid == 0) {
      int y = (lane < 16) ? part[lane] : 0;
      #pragma unroll
      for (int d = 1; d < 16; d <<= 1) { int o = __shfl_up(y, d); if (lane >= d) y += o; }
      if (lane < 16) part[lane] = y;
    }
    __syncthreads();
    int base = (wid > 0) ? part[wid - 1] : 0;
    return base + (x - s);
  };

  // ============ PHASE 1: Boruvka with edge compaction + barrier-free compression ============
  for (int v = tid; v < VV; v += nt) comp[v] = v;
  for (int e = tid; e < EE; e += nt) el0[e] = (unsigned short)e;
  if (tid == 0) cnt = 0;
  __syncthreads();
  {
    unsigned short* els = el0;
    unsigned short* eld = el1;
    int ecnt = EE;
    for (int round = 0; round < 48 && ecnt > 0; round++) {
      for (int v = tid; v < VV; v += nt) bst[v] = ~0ULL;
      if (tid == 0) { changed = 0; necnt = 0; }
      __syncthreads();
      for (int j = tid; j < ecnt; j += nt) {
        int e = els[j];
        int u, v; edge_uv(e, u, v);
        int cu = comp[u], cv = comp[v];
        if (cu != cv) { unsigned long long k = key[e]; atomicMin(&bst[cu], k); atomicMin(&bst[cv], k); }
      }
      __syncthreads();
      for (int c = tid; c < VV; c += nt) {
        unsigned short tg = (unsigned short)NILA;
        if (comp[c] == c) {
          unsigned long long k = bst[c];
          if (k != ~0ULL) {
            int e = (int)(k & 0x3FFFULL);
            int u, v; edge_uv(e, u, v);
            int cu = comp[u], cv = comp[v];
            tg = (unsigned short)((cu == c) ? cv : cu);
          }
        }
        tgtS[c] = tg;
      }
      __syncthreads();
      for (int c = tid; c < VV; c += nt) {
        int o = tgtS[c];
        if (o == (int)NILA) continue;
        unsigned long long k = bst[c];
        if (bst[o] == k && c < o) continue;  // mutual minimum edge: smaller id stays root
        comp[c] = o;
        int slot = atomicAdd(&cnt, 1);
        int e = (int)(k & 0x3FFFULL);
        int u, v; edge_uv(e, u, v);
        mu[slot] = u; mv[slot] = v;
        changed = 1;
      }
      __syncthreads();
      if (!changed) break;
      for (int v = tid; v < VV; v += nt) {
        int c = comp[v];
        int c2 = comp[c];
        if (c2 != c) {
          int r0 = c2;
          while (true) { int n = comp[r0]; if (n == r0) break; r0 = n; }
          comp[v] = r0;
        }
      }
      __syncthreads();
      for (int j = tid; j < ecnt; j += nt) {
        int e = els[j];
        int u, v; edge_uv(e, u, v);
        if (comp[u] != comp[v]) { int s = atomicAdd(&necnt, 1); eld[s] = (unsigned short)e; }
      }
      __syncthreads();
      ecnt = necnt;
      __syncthreads();
      unsigned short* tp = els; els = eld; eld = tp;
    }
  }
  __threadfence();
  __syncthreads();

  // ============ PHASE 2: Euler-tour center rooting (round-18 machinery) ============
  for (int v = tid; v < VV; v += nt) deg[v] = 0;
  __syncthreads();
  for (int e = tid; e < NE; e += nt) { atomicAdd(&deg[mu[e]], 1); atomicAdd(&deg[mv[e]], 1); }
  __syncthreads();
  {
    const int SCH = 7;
    int base = tid * SCH;
    int s = 0;
    #pragma unroll
    for (int k = 0; k < SCH; k++) { int v = base + k; if (v < VV) s += deg[v]; }
    int ex = blockScanEx(s);
    #pragma unroll
    for (int k = 0; k < SCH; k++) { int v = base + k; if (v < VV) { off[v] = ex; ex += deg[v]; } }
    if (tid == 1023) off[VV] = ex;
  }
  __syncthreads();
  for (int v = tid; v < VV; v += nt) deg[v] = off[v];
  __syncthreads();
  for (int e = tid; e < NE; e += nt) {
    int u = mu[e], v = mv[e];
    adjA[atomicAdd(&deg[u], 1)] = (unsigned short)(2 * e);
    adjA[atomicAdd(&deg[v], 1)] = (unsigned short)(2 * e + 1);
  }
  __syncthreads();
  for (int v = tid; v < VV; v += nt) {
    int b0 = off[v], dv = off[v + 1] - b0;
    for (int k = 0; k < dv; k++) {
      unsigned short a = adjA[b0 + k];
      unsigned short b = adjA[b0 + ((k + 1 == dv) ? 0 : k + 1)];
      succ[a ^ 1] = b;
    }
  }
  if (tid == 0) lasts = adjA[off[ROOT] + (off[ROOT + 1] - off[ROOT]) - 1] ^ 1;
  __syncthreads();
  if (tid == 0) succ[lasts] = (unsigned short)NILA;
  __syncthreads();
  for (int a = tid; a < NA; a += nt) {
    unsigned int n = succ[a];
    pk0[a] = ((n == NILA ? 0 : 1) << 16) | (int)n;
  }
  __syncthreads();
  {
    int* px = pk0;
    int* py = pk1;
    for (int rd = 0; rd < 14; rd++) {
      for (int a = tid; a < NA; a += nt) {
        int cur_ = px[a];
        int n = cur_ & 0xFFFF;
        if (n != (int)NILA) {
          int o = px[n];
          cur_ = (((cur_ >> 16) + (o >> 16)) << 16) | (o & 0xFFFF);
        }
        py[a] = cur_;
      }
      __syncthreads();
      int* tp = px; px = py; py = tp;
    }
    for (int a = tid; a < NA; a += nt) r_a[a] = (unsigned short)(pk0[a] >> 16);
  }
  __syncthreads();
  for (int a = tid; a < NA; a += nt) {
    int pa = NA - 1 - (int)r_a[a];
    int pb = NA - 1 - (int)r_a[a ^ 1];
    H[pa] = (pa < pb) ? (short)1 : (short)-1;
  }
  __syncthreads();
  {
    const int SCH = 13;
    int base = tid * SCH;
    int lim = base + SCH; if (lim > NA) lim = NA;
    int s = 0;
    for (int j = base; j < lim; j++) s += H[j];
    int run = blockScanEx(s);
    for (int j = base; j < lim; j++) { run += H[j]; H[j] = (short)run; }
  }
  __syncthreads();
  if (tid == 0) { spackU = 0; smaxd = 0; scenter = 0x7FFFFFFF; }
  __syncthreads();
  for (int a = tid; a < NA; a += nt) {
    int pa = NA - 1 - (int)r_a[a];
    int pb = NA - 1 - (int)r_a[a ^ 1];
    if (pa < pb) {
      int e = a >> 1;
      int head = (a & 1) ? mu[e] : mv[e];
      depthR[head] = (unsigned short)H[pa];
      firstK[head] = (unsigned short)(pa + 1);
    }
  }
  if (tid == 0) { depthR[ROOT] = 0; firstK[ROOT] = 0; }
  __syncthreads();
  {
    int loc = 0;
    for (int v = tid; v < VV; v += nt) { int p = ((int)depthR[v] << 13) | v; if (p > loc) loc = p; }
    #pragma unroll
    for (int d = 32; d > 0; d >>= 1) { int o = __shfl_down(loc, d); if (o > loc) loc = o; }
    if (lane == 0) atomicMax(&spackU, loc);
  }
  __syncthreads();
  {
    for (int seg = wid; seg < NB; seg += 16) {
      int p = seg * 64 + lane;
      int h = (p < NA) ? (int)H[p] : 32767;
      int hp = h;
      #pragma unroll
      for (int d = 1; d < 64; d <<= 1) { int o = __shfl_up(hp, d); if (lane >= d && o < hp) hp = o; }
      prefmin[p] = (short)hp;
      int hs = h;
      #pragma unroll
      for (int d = 1; d < 64; d <<= 1) { int o = __shfl_down(hs, d); if (lane + d < 64 && o < hs) hs = o; }
      sufmin[p] = (short)hs;
      if (lane == 0) tbl[seg] = (short)hs;
    }
  }
  __syncthreads();
  for (int k = 1; k < 8; k++) {
    short vv_ = 0;
    if (tid < NB) {
      int o = tid + (1 << (k - 1));
      short a = tbl[(k - 1) * NB + tid];
      short b2 = (o < NB) ? tbl[(k - 1) * NB + o] : (short)32767;
      vv_ = (a < b2) ? a : b2;
    }
    __syncthreads();
    if (tid < NB) tbl[k * NB + tid] = vv_;
    __syncthreads();
  }
  auto distq = [&](int K1, int K2) -> int {
    if (K1 == K2) return 0;
    int l = (K1 < K2 ? K1 : K2) - 1;
    int r = (K1 > K2 ? K1 : K2) - 1;
    int m = 32767;
    int l0 = l < 0 ? 0 : l;
    int bl = l0 >> 6, br = r >> 6;
    if (bl == br) {
      for (int p = l0; p <= r; p++) { int h = H[p]; if (h < m) m = h; }
    } else {
      int a = sufmin[l0], b2 = prefmin[r];
      m = a < b2 ? a : b2;
      int lo = bl + 1, hi = br - 1;
      if (lo <= hi) {
        int L = hi - lo + 1;
        int k = 31 - __builtin_clz(L);
        int c1 = tbl[k * NB + lo];
        int c2 = tbl[k * NB + hi - (1 << k) + 1];
        if (c1 < m) m = c1;
        if (c2 < m) m = c2;
      }
    }
    if (l < 0 && 0 < m) m = 0;
    int h1 = (K1 == 0) ? 0 : (int)H[K1 - 1];
    int h2 = (K2 == 0) ? 0 : (int)H[K2 - 1];
    return h1 + h2 - 2 * m;
  };
  int u = spackU & 0x1FFF;
  int Ku = firstK[u];
  if (tid == 0) spackW = 0;
  __syncthreads();
  {
    int loc = 0;
    for (int v = tid; v < VV; v += nt) {
      int d = distq(Ku, firstK[v]);
      distU[v] = (unsigned short)d;
      int p = (d << 13) | v;
      if (p > loc) loc = p;
    }
    #pragma unroll
    for (int d = 32; d > 0; d >>= 1) { int o = __shfl_down(loc, d); if (o > loc) loc = o; }
    if (lane == 0) atomicMax(&spackW, loc);
  }
  __syncthreads();
  int D = spackW >> 13;
  int w = spackW & 0x1FFF;
  int Kw = firstK[w];
  for (int v = tid; v < VV; v += nt) dbuf2[v] = (unsigned short)distq(Kw, firstK[v]);
  __syncthreads();
  {
    int half = D >> 1;
    for (int v = tid; v < VV; v += nt) {
      if ((int)distU[v] == half && (int)distU[v] + (int)dbuf2[v] == D) atomicMin(&scenter, v);
    }
  }
  __syncthreads();
  int cvert = (scenter == 0x7FFFFFFF) ? ROOT : scenter;
  int Kc = firstK[cvert];
  __syncthreads();
  {
    int loc = 0;
    for (int v = tid; v < VV; v += nt) {
      int d = distq(Kc, firstK[v]);
      dbuf2[v] = (unsigned short)d;
      if (d > loc) loc = d;
    }
    #pragma unroll
    for (int d = 32; d > 0; d >>= 1) { int o = __shfl_down(loc, d); if (o > loc) loc = o; }
    if (lane == 0) atomicMax(&smaxd, loc);
  }
  __syncthreads();
  int maxd = smaxd;
  int sTil = Kc;
  for (int a = tid; a < NA; a += nt) {
    int pa = NA - 1 - (int)r_a[a];
    int pb = NA - 1 - (int)r_a[a ^ 1];
    int pa2 = pa - sTil; if (pa2 < 0) pa2 += NA;
    int pb2 = pb - sTil; if (pb2 < 0) pb2 += NA;
    if (pa2 < pb2) {
      int e = a >> 1;
      int head = (a & 1) ? mu[e] : mv[e];
      int tail = (a & 1) ? mv[e] : mu[e];
      parentS[head] = (unsigned short)tail;
    }
  }
  if (tid == 0) parentS[cvert] = (unsigned short)cvert;
  __syncthreads();
  // ---- counting sort by dist-from-center ----
  for (int d = tid; d <= VV; d += nt) lev[d] = 0;
  __syncthreads();
  for (int v = tid; v < VV; v += nt) atomicAdd(&lev[dbuf2[v]], 1);
  __syncthreads();
  {
    const int SCH = 7;
    int base = tid * SCH;
    int s = 0;
    #pragma unroll
    for (int k = 0; k < SCH; k++) { int d = base + k; if (d <= VV) s += lev[d]; }
    int ex = blockScanEx(s);
    #pragma unroll
    for (int k = 0; k < SCH; k++) {
      int d = base + k;
      if (d <= VV) {
        int st = ex;
        ex += lev[d];
        if (d < VV) cur[d] = st;
        lpG[t * (VV + 1) + d] = st;
      }
    }
  }
  __syncthreads();
  for (int v = tid; v < VV; v += nt) {
    int d = dbuf2[v];
    int slot = atomicAdd(&cur[d], 1);
    ordS[slot] = (unsigned short)v;
    posS[v] = (unsigned short)slot;
  }
  __syncthreads();
  // ---- emit ord/sp + FUSED weights (from LDS, no pvG round-trip) ----
  for (int j = tid; j < VV; j += nt) {
    int v = ordS[j];
    int pv = parentS[v];
    ordG[t * VV + j] = v;
    spG[t * VV + j] = posS[pv];
    float wout;
    if (v == pv) {
      wout = 1.0f;  // root (filter transform special-cases pos 0)
    } else {
      int a = v < pv ? v : pv;
      int diff = v < pv ? pv - v : v - pv;
      int e;
      if (diff == WW) e = a;
      else { int r = a / WW, c = a - r * WW; e = EVERT + r * (WW - 1) + c; }
      unsigned long long k = key[e];
      double cost = __longlong_as_double((long long)(k & ~0x3FFFULL));
      wout = expf(-(float)cost / SIGMA_F);
    }
    wvp[t * VV + j] = wout;
  }
  if (tid == 0) nlevG[t] = maxd + 1;
}

// ---------------- K6: tree filter — level-sweep up (wave 0), packed-float2 doubling down ----------------
// (Round-18 verbatim.)
__global__ __launch_bounds__(512) void k_filter_pc(const float* __restrict__ Fsrc, float* __restrict__ Araw,
    const float* __restrict__ wvp, const int* __restrict__ ordG, const int* __restrict__ spG,
    const int* __restrict__ lpG, const int* __restrict__ nlevG, int treeBase) {
  int blk = blockIdx.x;
  int b = blk / CF, ch = blk - b * CF;
  int t = treeBase + b;
  __shared__ alignas(16) char arena[140816];
  float2* ab0 = (float2*)(arena);
  float2* ab1 = (float2*)(arena + 51200);
  float*  S   = (float*)(arena + 51200);
  float*  w   = (float*)(arena + 76800);
  unsigned short* sp0 = (unsigned short*)(arena + 102400);
  unsigned short* sp1 = (unsigned short*)(arena + 115200);
  unsigned short* lpS = (unsigned short*)(arena + 128000);
  const int* ord = ordG + t * VV;
  const int* spt = spG + t * VV;
  const float* wsrc = wvp + t * VV;
  const int* lp = lpG + t * (VV + 1);
  int tid = threadIdx.x;
  const int nt = 512;
  int NL = nlevG[t];
  for (int j = tid; j <= NL; j += nt) lpS[j] = (unsigned short)lp[j];
  const bool norm_in = (treeBase != 0);
  for (int j = tid; j < VV; j += nt) {
    sp0[j] = (unsigned short)spt[j];
    w[j] = wsrc[j];
    float val;
    if (ch < CP) {
      int v = ord[j];
      if (!norm_in) val = Fsrc[((size_t)b * CP + ch) * VV + v];
      else          val = Fsrc[((size_t)b * CF + ch) * VV + v] / Fsrc[((size_t)b * CF + CP) * VV + v];
    } else val = 1.0f;
    S[j] = val;
  }
  __syncthreads();
  if (tid < 64) {
    int s1 = lpS[NL];
    int s0 = lpS[NL - 1];
    for (int l = NL - 1; l >= 1; l--) {
      int s0n = (l > 1) ? (int)lpS[l - 1] : 0;
      for (int j = s0 + tid; j < s1; j += 64) {
        atomicAdd(&S[sp0[j]], w[j] * S[j]);
      }
      asm volatile("s_waitcnt lgkmcnt(0)" ::: "memory");
      __builtin_amdgcn_sched_barrier(0);
      s1 = s0; s0 = s0n;
    }
  }
  __syncthreads();
  for (int j = tid; j < VV; j += nt) {
    float wv = w[j];
    float a = (j == 0) ? 0.f : wv;
    float bv = (j == 0) ? S[0] : S[j] * (1.f - wv * wv);
    ab0[j] = make_float2(a, bv);
  }
  __syncthreads();
  int rounds = 0;
  { int d = 1; while (d < NL) { d <<= 1; rounds++; } }
  float2 *abs_ = ab0, *abd_ = ab1;
  unsigned short *ps_ = sp0, *pd_ = sp1;
  for (int r = 0; r < rounds; r++) {
    for (int j = tid; j < VV; j += nt) {
      float2 m = abs_[j];
      int p = ps_[j];
      float2 o = m;
      int pn = p;
      if (m.x != 0.f) {
        float2 mp = abs_[p];
        pn = ps_[p];
        o.x = m.x * mp.x;
        o.y = fmaf(m.x, mp.y, m.y);
      }
      abd_[j] = o;
      pd_[j] = (unsigned short)pn;
    }
    __syncthreads();
    float2* tf = abs_; abs_ = abd_; abd_ = tf;
    unsigned short* tu = ps_; ps_ = pd_; pd_ = tu;
  }
  float* Ob = Araw + ((size_t)b * CF + ch) * VV;
  for (int j = tid; j < VV; j += nt) Ob[ord[j]] = abs_[j].y;
}

// ---------------- K7: ROI-masked L1 loss (fused normalize of stage 2) ----------------
__global__ void k_loss(const float* __restrict__ prob, const float* __restrict__ Araw2,
                       const int* __restrict__ roi, double* __restrict__ acc) {
  int i = blockIdx.x * blockDim.x + threadIdx.x;
  int tid = threadIdx.x;
  double s = 0.0, n = 0.0;
  if (i < BB * VV) {
    int b = i / VV, v = i - b * VV;
    if (roi[i] != 0) {
      n = 1.0;
      const float* pb = prob + (size_t)b * CP * VV + v;
      const float* ab = Araw2 + (size_t)b * CF * VV + v;
      float inv = 1.0f / ab[CP * VV];
      float ls = 0.f;
      #pragma unroll
      for (int c = 0; c < CP; c++) ls += fabsf(pb[c * VV] - ab[c * VV] * inv);
      s = (double)ls;
    }
  }
  __shared__ double rs[256], rn[256];
  rs[tid] = s; rn[tid] = n;
  __syncthreads();
  for (int d = 128; d > 0; d >>= 1) {
    if (tid < d) { rs[tid] += rs[tid + d]; rn[tid] += rn[tid + d]; }
    __syncthreads();
  }
  if (tid == 0) { atomicAdd(&acc[0], rs[0]); atomicAdd(&acc[1], rn[0]); }
}

__global__ void k_finalize(const double* __restrict__ acc, float* __restrict__ out) {
  out[0] = (acc[1] > 0.0) ? (float)(acc[0] / acc[1]) : 0.0f;
}

extern "C" void kernel_launch(void* const* d_in, const int* in_sizes, int n_in,
                              void* d_out, int out_size, void* d_ws, size_t ws_size,
                              hipStream_t stream) {
  const float* preds = (const float*)d_in[0];
  const float* low   = (const float*)d_in[1];
  const float* high  = (const float*)d_in[2];
  const int*   roi   = (const int*)d_in[3];
  float* out = (float*)d_out;

  char* w = (char*)d_ws;
  size_t off = 0;
  auto alloc = [&](size_t bytes) -> void* {
    void* p = w + off;
    off += (bytes + 255) & ~(size_t)255;
    return p;
  };
  float* prob  = (float*)alloc((size_t)BB * CP * VV * 4);
  float* Araw1 = (float*)alloc((size_t)BB * CF * VV * 4);
  float* Araw2 = (float*)alloc((size_t)BB * CF * VV * 4);
  unsigned long long* ekey = (unsigned long long*)alloc((size_t)TT * EE * 8);
  int* mstU = (int*)alloc((size_t)TT * VV * 4);
  int* mstV = (int*)alloc((size_t)TT * VV * 4);
  int* ordG = (int*)alloc((size_t)TT * VV * 4);
  int* spG  = (int*)alloc((size_t)TT * VV * 4);
  int* lpG  = (int*)alloc((size_t)TT * (VV + 1) * 4);
  int* nlev = (int*)alloc((size_t)TT * 4);
  float* wvp = (float*)alloc((size_t)TT * VV * 4);
  double* acc = (double*)alloc(16);

  hipMemsetAsync(acc, 0, 16, stream);

  k_softmax<<<(BB * VV + 255) / 256, 256, 0, stream>>>(preds, prob);
  k_edgekey<<<(TT * EE + 255) / 256, 256, 0, stream>>>(low, high, ekey);
  k_msttree<<<TT, 1024, 0, stream>>>(ekey, mstU, mstV, ordG, spG, lpG, nlev, wvp);
  k_filter_pc<<<BB * CF, 512, 0, stream>>>(prob,  Araw1, wvp, ordG, spG, lpG, nlev, 0);
  k_filter_pc<<<BB * CF, 512, 0, stream>>>(Araw1, Araw2, wvp, ordG, spG, lpG, nlev, BB);
  k_loss<<<(BB * VV + 255) / 256, 256, 0, stream>>>(prob, Araw2, roi, acc);
  k_finalize<<<1, 1, 0, stream>>>(acc, out);
}

// Round 22
// 278.283 us; speedup vs baseline: 1.5089x; 1.0819x over previous
//
#include <hip/hip_runtime.h>

#define BB 8
#define CP 21
#define CF 22
#define CLOW 3
#define CHIGH 256
#define WW 80
#define VV 6400
#define EVERT 6320
#define EE 12640
#define TT 16
#define SIGMA_F 0.002f
#define ROOT 3240          // seed vertex for tour break / diameter search

#define NE (VV - 1)        // tree edges
#define NA (2 * NE)        // Euler arcs = 12798
#define NILA 0xFFFFu
#define NB 200             // ceil(NA/64) RMQ blocks
#define SMB ((BB * VV + 255) / 256)   // softmax blocks = 200

__device__ __forceinline__ void edge_uv(int e, int& u, int& v) {
  if (e < EVERT) { u = e; v = e + WW; }
  else { int e2 = e - EVERT; int r = e2 / (WW - 1); int c = e2 - r * (WW - 1); u = r * WW + c; v = u + 1; }
}

// ---------------- K2: edge keys (float64 cost, top-50-bits | edge idx) ----------------
__global__ void k_edgekey(const float* __restrict__ low, const float* __restrict__ high,
                          unsigned long long* __restrict__ ekey) {
  int i = blockIdx.x * blockDim.x + threadIdx.x;
  if (i >= TT * EE) return;
  int t = i / EE, e = i - t * EE;
  int u, v; edge_uv(e, u, v);
  double acc = 0.0;
  if (t < BB) {
    const float* emb = low + (size_t)t * CLOW * VV;
    for (int c = 0; c < CLOW; c++) { double d = (double)emb[c * VV + u] - (double)emb[c * VV + v]; acc += d * d; }
  } else {
    const float* emb = high + (size_t)(t - BB) * CHIGH * VV;
    for (int c = 0; c < CHIGH; c++) { double d = (double)emb[c * VV + u] - (double)emb[c * VV + v]; acc += d * d; }
  }
  unsigned long long bits = (unsigned long long)__double_as_longlong(acc);
  ekey[i] = (bits & ~0x3FFFULL) | (unsigned long long)e;
}

// ---------------- K3: FUSED: per-tree MST+rooting+weights (blocks 0..15) | softmax (blocks 16+) ----------------
__global__ __launch_bounds__(1024) void k_msttree(const unsigned long long* __restrict__ ekey,
    int* __restrict__ mstU, int* __restrict__ mstV,
    int* __restrict__ ordG, int* __restrict__ spG,
    int* __restrict__ lpG, int* __restrict__ nlevG, float* __restrict__ wvp,
    const float* __restrict__ preds, float* __restrict__ prob) {
  if (blockIdx.x >= TT) {
    // ---- softmax side-car: 1024 threads, 4 pixels... grid sized so each thread does 1 pixel via flat index ----
    int i = (blockIdx.x - TT) * 1024 + threadIdx.x;
    if (i < BB * VV) {
      int b = i / VV, v = i - b * VV;
      const float* p = preds + (size_t)b * CP * VV + v;
      float m = -1e30f;
      #pragma unroll
      for (int c = 0; c < CP; c++) m = fmaxf(m, p[c * VV]);
      float e[CP], s = 0.f;
      #pragma unroll
      for (int c = 0; c < CP; c++) { float x = expf(p[c * VV] - m); e[c] = x; s += x; }
      float inv = 1.f / s;
      float* o = prob + (size_t)b * CP * VV + v;
      #pragma unroll
      for (int c = 0; c < CP; c++) o[c * VV] = e[c] * inv;
    }
    return;
  }
  int t = blockIdx.x;
  const unsigned long long* key = ekey + (size_t)t * EE;
  int* mu = mstU + t * VV;
  int* mv = mstV + t * VV;
  int tid = threadIdx.x;
  const int nt = 1024;
  int lane = tid & 63, wid = tid >> 6;

  __shared__ alignas(16) char arena[144384];
  __shared__ int lasts, spackU, spackW, scenter, smaxd, changed, cnt, necnt;

  // ===== Phase 1 regions (Boruvka) =====
  int* comp = (int*)(arena + 0);
  unsigned long long* bst = (unsigned long long*)(arena + 25600);
  unsigned short* tgtS = (unsigned short*)(arena + 76800);
  unsigned short* el0 = (unsigned short*)(arena + 89600);
  unsigned short* el1 = (unsigned short*)(arena + 114880);

  // ===== Phase 2 regions (Euler rooting; overlays Phase 1) =====
  char* buf = arena;
  int* deg = (int*)(buf + 0);
  int* off = (int*)(buf + 25600);
  unsigned short* adjA = (unsigned short*)(buf + 51208);
  unsigned short* succ = (unsigned short*)(buf + 102408);
  int* pk0 = (int*)(buf + 0);
  int* pk1 = (int*)(buf + 51208);
  unsigned short* r_a = (unsigned short*)(buf + 102408);
  short* H = (short*)(buf + 51208);
  unsigned short* depthR = (unsigned short*)(buf + 76808);
  unsigned short* firstK = (unsigned short*)(buf + 89608);
  short* prefmin = (short*)(buf + 0);
  short* sufmin  = (short*)(buf + 25600);
  unsigned short* distU = (unsigned short*)(buf + 76808);
  unsigned short* parentS = (unsigned short*)(buf + 76808);
  int* lev = (int*)(buf + 0);
  int* cur = (int*)(buf + 25604);
  unsigned short* ordS = (unsigned short*)(buf + 51208);
  unsigned short* posS = (unsigned short*)(buf + 64008);
  int* part = (int*)(buf + 128016);
  short* tbl = (short*)(buf + 128272);
  unsigned short* dbuf2 = (unsigned short*)(buf + 131472);

  auto blockScanEx = [&](int s) -> int {
    int x = s;
    #pragma unroll
    for (int d = 1; d < 64; d <<= 1) { int o = __shfl_up(x, d); if (lane >= d) x += o; }
    if (lane == 63) part[wid] = x;
    __syncthreads();
    if (wid == 0) {
      int y = (lane < 16) ? part[lane] : 0;
      #pragma unroll
      for (int d = 1; d < 16; d <<= 1) { int o = __shfl_up(y, d); if (lane >= d) y += o; }
      if (lane < 16) part[lane] = y;
    }
    __syncthreads();
    int base = (wid > 0) ? part[wid - 1] : 0;
    return base + (x - s);
  };

  // ============ PHASE 1: Boruvka ============
  for (int v = tid; v < VV; v += nt) comp[v] = v;
  for (int e = tid; e < EE; e += nt) el0[e] = (unsigned short)e;
  if (tid == 0) cnt = 0;
  __syncthreads();
  {
    unsigned short* els = el0;
    unsigned short* eld = el1;
    int ecnt = EE;
    for (int round = 0; round < 48 && ecnt > 0; round++) {
      for (int v = tid; v < VV; v += nt) bst[v] = ~0ULL;
      if (tid == 0) { changed = 0; necnt = 0; }
      __syncthreads();
      for (int j = tid; j < ecnt; j += nt) {
        int e = els[j];
        int u, v; edge_uv(e, u, v);
        int cu = comp[u], cv = comp[v];
        if (cu != cv) { unsigned long long k = key[e]; atomicMin(&bst[cu], k); atomicMin(&bst[cv], k); }
      }
      __syncthreads();
      for (int c = tid; c < VV; c += nt) {
        unsigned short tg = (unsigned short)NILA;
        if (comp[c] == c) {
          unsigned long long k = bst[c];
          if (k != ~0ULL) {
            int e = (int)(k & 0x3FFFULL);
            int u, v; edge_uv(e, u, v);
            int cu = comp[u], cv = comp[v];
            tg = (unsigned short)((cu == c) ? cv : cu);
          }
        }
        tgtS[c] = tg;
      }
      __syncthreads();
      for (int c = tid; c < VV; c += nt) {
        int o = tgtS[c];
        if (o == (int)NILA) continue;
        unsigned long long k = bst[c];
        if (bst[o] == k && c < o) continue;  // mutual minimum edge
        comp[c] = o;
        int slot = atomicAdd(&cnt, 1);
        int e = (int)(k & 0x3FFFULL);
        int u, v; edge_uv(e, u, v);
        mu[slot] = u; mv[slot] = v;
        changed = 1;
      }
      __syncthreads();
      if (!changed) break;
      for (int v = tid; v < VV; v += nt) {
        int c = comp[v];
        int c2 = comp[c];
        if (c2 != c) {
          int r0 = c2;
          while (true) { int n = comp[r0]; if (n == r0) break; r0 = n; }
          comp[v] = r0;
        }
      }
      __syncthreads();
      for (int j = tid; j < ecnt; j += nt) {
        int e = els[j];
        int u, v; edge_uv(e, u, v);
        if (comp[u] != comp[v]) { int s = atomicAdd(&necnt, 1); eld[s] = (unsigned short)e; }
      }
      __syncthreads();
      ecnt = necnt;
      __syncthreads();
      unsigned short* tp = els; els = eld; eld = tp;
    }
  }
  __threadfence();
  __syncthreads();

  // ============ PHASE 2: Euler-tour center rooting ============
  for (int v = tid; v < VV; v += nt) deg[v] = 0;
  __syncthreads();
  for (int e = tid; e < NE; e += nt) { atomicAdd(&deg[mu[e]], 1); atomicAdd(&deg[mv[e]], 1); }
  __syncthreads();
  {
    const int SCH = 7;
    int base = tid * SCH;
    int s = 0;
    #pragma unroll
    for (int k = 0; k < SCH; k++) { int v = base + k; if (v < VV) s += deg[v]; }
    int ex = blockScanEx(s);
    #pragma unroll
    for (int k = 0; k < SCH; k++) { int v = base + k; if (v < VV) { off[v] = ex; ex += deg[v]; } }
    if (tid == 1023) off[VV] = ex;
  }
  __syncthreads();
  for (int v = tid; v < VV; v += nt) deg[v] = off[v];
  __syncthreads();
  for (int e = tid; e < NE; e += nt) {
    int u = mu[e], v = mv[e];
    adjA[atomicAdd(&deg[u], 1)] = (unsigned short)(2 * e);
    adjA[atomicAdd(&deg[v], 1)] = (unsigned short)(2 * e + 1);
  }
  __syncthreads();
  for (int v = tid; v < VV; v += nt) {
    int b0 = off[v], dv = off[v + 1] - b0;
    for (int k = 0; k < dv; k++) {
      unsigned short a = adjA[b0 + k];
      unsigned short b = adjA[b0 + ((k + 1 == dv) ? 0 : k + 1)];
      succ[a ^ 1] = b;
    }
  }
  if (tid == 0) lasts = adjA[off[ROOT] + (off[ROOT + 1] - off[ROOT]) - 1] ^ 1;
  __syncthreads();
  if (tid == 0) succ[lasts] = (unsigned short)NILA;
  __syncthreads();
  for (int a = tid; a < NA; a += nt) {
    unsigned int n = succ[a];
    pk0[a] = ((n == NILA ? 0 : 1) << 16) | (int)n;
  }
  __syncthreads();
  {
    int* px = pk0;
    int* py = pk1;
    for (int rd = 0; rd < 14; rd++) {
      for (int a = tid; a < NA; a += nt) {
        int cur_ = px[a];
        int n = cur_ & 0xFFFF;
        if (n != (int)NILA) {
          int o = px[n];
          cur_ = (((cur_ >> 16) + (o >> 16)) << 16) | (o & 0xFFFF);
        }
        py[a] = cur_;
      }
      __syncthreads();
      int* tp = px; px = py; py = tp;
    }
    for (int a = tid; a < NA; a += nt) r_a[a] = (unsigned short)(pk0[a] >> 16);
  }
  __syncthreads();
  for (int a = tid; a < NA; a += nt) {
    int pa = NA - 1 - (int)r_a[a];
    int pb = NA - 1 - (int)r_a[a ^ 1];
    H[pa] = (pa < pb) ? (short)1 : (short)-1;
  }
  __syncthreads();
  {
    const int SCH = 13;
    int base = tid * SCH;
    int lim = base + SCH; if (lim > NA) lim = NA;
    int s = 0;
    for (int j = base; j < lim; j++) s += H[j];
    int run = blockScanEx(s);
    for (int j = base; j < lim; j++) { run += H[j]; H[j] = (short)run; }
  }
  __syncthreads();
  if (tid == 0) { spackU = 0; smaxd = 0; scenter = 0x7FFFFFFF; }
  __syncthreads();
  for (int a = tid; a < NA; a += nt) {
    int pa = NA - 1 - (int)r_a[a];
    int pb = NA - 1 - (int)r_a[a ^ 1];
    if (pa < pb) {
      int e = a >> 1;
      int head = (a & 1) ? mu[e] : mv[e];
      depthR[head] = (unsigned short)H[pa];
      firstK[head] = (unsigned short)(pa + 1);
    }
  }
  if (tid == 0) { depthR[ROOT] = 0; firstK[ROOT] = 0; }
  __syncthreads();
  {
    int loc = 0;
    for (int v = tid; v < VV; v += nt) { int p = ((int)depthR[v] << 13) | v; if (p > loc) loc = p; }
    #pragma unroll
    for (int d = 32; d > 0; d >>= 1) { int o = __shfl_down(loc, d); if (o > loc) loc = o; }
    if (lane == 0) atomicMax(&spackU, loc);
  }
  __syncthreads();
  {
    for (int seg = wid; seg < NB; seg += 16) {
      int p = seg * 64 + lane;
      int h = (p < NA) ? (int)H[p] : 32767;
      int hp = h;
      #pragma unroll
      for (int d = 1; d < 64; d <<= 1) { int o = __shfl_up(hp, d); if (lane >= d && o < hp) hp = o; }
      prefmin[p] = (short)hp;
      int hs = h;
      #pragma unroll
      for (int d = 1; d < 64; d <<= 1) { int o = __shfl_down(hs, d); if (lane + d < 64 && o < hs) hs = o; }
      sufmin[p] = (short)hs;
      if (lane == 0) tbl[seg] = (short)hs;
    }
  }
  __syncthreads();
  for (int k = 1; k < 8; k++) {
    short vv_ = 0;
    if (tid < NB) {
      int o = tid + (1 << (k - 1));
      short a = tbl[(k - 1) * NB + tid];
      short b2 = (o < NB) ? tbl[(k - 1) * NB + o] : (short)32767;
      vv_ = (a < b2) ? a : b2;
    }
    __syncthreads();
    if (tid < NB) tbl[k * NB + tid] = vv_;
    __syncthreads();
  }
  auto distq = [&](int K1, int K2) -> int {
    if (K1 == K2) return 0;
    int l = (K1 < K2 ? K1 : K2) - 1;
    int r = (K1 > K2 ? K1 : K2) - 1;
    int m = 32767;
    int l0 = l < 0 ? 0 : l;
    int bl = l0 >> 6, br = r >> 6;
    if (bl == br) {
      for (int p = l0; p <= r; p++) { int h = H[p]; if (h < m) m = h; }
    } else {
      int a = sufmin[l0], b2 = prefmin[r];
      m = a < b2 ? a : b2;
      int lo = bl + 1, hi = br - 1;
      if (lo <= hi) {
        int L = hi - lo + 1;
        int k = 31 - __builtin_clz(L);
        int c1 = tbl[k * NB + lo];
        int c2 = tbl[k * NB + hi - (1 << k) + 1];
        if (c1 < m) m = c1;
        if (c2 < m) m = c2;
      }
    }
    if (l < 0 && 0 < m) m = 0;
    int h1 = (K1 == 0) ? 0 : (int)H[K1 - 1];
    int h2 = (K2 == 0) ? 0 : (int)H[K2 - 1];
    return h1 + h2 - 2 * m;
  };
  int u = spackU & 0x1FFF;
  int Ku = firstK[u];
  if (tid == 0) spackW = 0;
  __syncthreads();
  {
    int loc = 0;
    for (int v = tid; v < VV; v += nt) {
      int d = distq(Ku, firstK[v]);
      distU[v] = (unsigned short)d;
      int p = (d << 13) | v;
      if (p > loc) loc = p;
    }
    #pragma unroll
    for (int d = 32; d > 0; d >>= 1) { int o = __shfl_down(loc, d); if (o > loc) loc = o; }
    if (lane == 0) atomicMax(&spackW, loc);
  }
  __syncthreads();
  int D = spackW >> 13;
  int w = spackW & 0x1FFF;
  int Kw = firstK[w];
  for (int v = tid; v < VV; v += nt) dbuf2[v] = (unsigned short)distq(Kw, firstK[v]);
  __syncthreads();
  {
    int half = D >> 1;
    for (int v = tid; v < VV; v += nt) {
      if ((int)distU[v] == half && (int)distU[v] + (int)dbuf2[v] == D) atomicMin(&scenter, v);
    }
  }
  __syncthreads();
  int cvert = (scenter == 0x7FFFFFFF) ? ROOT : scenter;
  int Kc = firstK[cvert];
  __syncthreads();
  {
    int loc = 0;
    for (int v = tid; v < VV; v += nt) {
      int d = distq(Kc, firstK[v]);
      dbuf2[v] = (unsigned short)d;
      if (d > loc) loc = d;
    }
    #pragma unroll
    for (int d = 32; d > 0; d >>= 1) { int o = __shfl_down(loc, d); if (o > loc) loc = o; }
    if (lane == 0) atomicMax(&smaxd, loc);
  }
  __syncthreads();
  int maxd = smaxd;
  int sTil = Kc;
  for (int a = tid; a < NA; a += nt) {
    int pa = NA - 1 - (int)r_a[a];
    int pb = NA - 1 - (int)r_a[a ^ 1];
    int pa2 = pa - sTil; if (pa2 < 0) pa2 += NA;
    int pb2 = pb - sTil; if (pb2 < 0) pb2 += NA;
    if (pa2 < pb2) {
      int e = a >> 1;
      int head = (a & 1) ? mu[e] : mv[e];
      int tail = (a & 1) ? mv[e] : mu[e];
      parentS[head] = (unsigned short)tail;
    }
  }
  if (tid == 0) parentS[cvert] = (unsigned short)cvert;
  __syncthreads();
  for (int d = tid; d <= VV; d += nt) lev[d] = 0;
  __syncthreads();
  for (int v = tid; v < VV; v += nt) atomicAdd(&lev[dbuf2[v]], 1);
  __syncthreads();
  {
    const int SCH = 7;
    int base = tid * SCH;
    int s = 0;
    #pragma unroll
    for (int k = 0; k < SCH; k++) { int d = base + k; if (d <= VV) s += lev[d]; }
    int ex = blockScanEx(s);
    #pragma unroll
    for (int k = 0; k < SCH; k++) {
      int d = base + k;
      if (d <= VV) {
        int st = ex;
        ex += lev[d];
        if (d < VV) cur[d] = st;
        lpG[t * (VV + 1) + d] = st;
      }
    }
  }
  __syncthreads();
  for (int v = tid; v < VV; v += nt) {
    int d = dbuf2[v];
    int slot = atomicAdd(&cur[d], 1);
    ordS[slot] = (unsigned short)v;
    posS[v] = (unsigned short)slot;
  }
  __syncthreads();
  for (int j = tid; j < VV; j += nt) {
    int v = ordS[j];
    int pv = parentS[v];
    ordG[t * VV + j] = v;
    spG[t * VV + j] = posS[pv];
    float wout;
    if (v == pv) {
      wout = 1.0f;  // root (filter transform special-cases pos 0)
    } else {
      int a = v < pv ? v : pv;
      int diff = v < pv ? pv - v : v - pv;
      int e;
      if (diff == WW) e = a;
      else { int r = a / WW, c = a - r * WW; e = EVERT + r * (WW - 1) + c; }
      unsigned long long k = key[e];
      double cost = __longlong_as_double((long long)(k & ~0x3FFFULL));
      wout = expf(-(float)cost / SIGMA_F);
    }
    wvp[t * VV + j] = wout;
  }
  if (tid == 0) nlevG[t] = maxd + 1;
}

// ---------------- K6: tree filter — 1024 threads; level-sweep up (wave 0), float2 doubling down ----------------
__global__ __launch_bounds__(1024) void k_filter_pc(const float* __restrict__ Fsrc, float* __restrict__ Araw,
    const float* __restrict__ wvp, const int* __restrict__ ordG, const int* __restrict__ spG,
    const int* __restrict__ lpG, const int* __restrict__ nlevG, int treeBase) {
  int blk = blockIdx.x;
  int b = blk / CF, ch = blk - b * CF;
  int t = treeBase + b;
  __shared__ alignas(16) char arena[140816];
  float2* ab0 = (float2*)(arena);
  float2* ab1 = (float2*)(arena + 51200);
  float*  S   = (float*)(arena + 51200);
  float*  w   = (float*)(arena + 76800);
  unsigned short* sp0 = (unsigned short*)(arena + 102400);
  unsigned short* sp1 = (unsigned short*)(arena + 115200);
  unsigned short* lpS = (unsigned short*)(arena + 128000);
  const int* ord = ordG + t * VV;
  const int* spt = spG + t * VV;
  const float* wsrc = wvp + t * VV;
  const int* lp = lpG + t * (VV + 1);
  int tid = threadIdx.x;
  const int nt = 1024;
  int NL = nlevG[t];
  for (int j = tid; j <= NL; j += nt) lpS[j] = (unsigned short)lp[j];
  const bool norm_in = (treeBase != 0);
  for (int j = tid; j < VV; j += nt) {
    sp0[j] = (unsigned short)spt[j];
    w[j] = wsrc[j];
    float val;
    if (ch < CP) {
      int v = ord[j];
      if (!norm_in) val = Fsrc[((size_t)b * CP + ch) * VV + v];
      else          val = Fsrc[((size_t)b * CF + ch) * VV + v] / Fsrc[((size_t)b * CF + CP) * VV + v];
    } else val = 1.0f;
    S[j] = val;
  }
  __syncthreads();
  if (tid < 64) {
    int s1 = lpS[NL];
    int s0 = lpS[NL - 1];
    for (int l = NL - 1; l >= 1; l--) {
      int s0n = (l > 1) ? (int)lpS[l - 1] : 0;
      for (int j = s0 + tid; j < s1; j += 64) {
        atomicAdd(&S[sp0[j]], w[j] * S[j]);
      }
      asm volatile("s_waitcnt lgkmcnt(0)" ::: "memory");
      __builtin_amdgcn_sched_barrier(0);
      s1 = s0; s0 = s0n;
    }
  }
  __syncthreads();
  for (int j = tid; j < VV; j += nt) {
    float wv = w[j];
    float a = (j == 0) ? 0.f : wv;
    float bv = (j == 0) ? S[0] : S[j] * (1.f - wv * wv);
    ab0[j] = make_float2(a, bv);
  }
  __syncthreads();
  int rounds = 0;
  { int d = 1; while (d < NL) { d <<= 1; rounds++; } }
  float2 *abs_ = ab0, *abd_ = ab1;
  unsigned short *ps_ = sp0, *pd_ = sp1;
  for (int r = 0; r < rounds; r++) {
    for (int j = tid; j < VV; j += nt) {
      float2 m = abs_[j];
      int p = ps_[j];
      float2 o = m;
      int pn = p;
      if (m.x != 0.f) {
        float2 mp = abs_[p];
        pn = ps_[p];
        o.x = m.x * mp.x;
        o.y = fmaf(m.x, mp.y, m.y);
      }
      abd_[j] = o;
      pd_[j] = (unsigned short)pn;
    }
    __syncthreads();
    float2* tf = abs_; abs_ = abd_; abd_ = tf;
    unsigned short* tu = ps_; ps_ = pd_; pd_ = tu;
  }
  float* Ob = Araw + ((size_t)b * CF + ch) * VV;
  for (int j = tid; j < VV; j += nt) Ob[ord[j]] = abs_[j].y;
}

// ---------------- K7: ROI-masked L1 loss with fused finalize (last-block-done) ----------------
__global__ void k_loss(const float* __restrict__ prob, const float* __restrict__ Araw2,
                       const int* __restrict__ roi, double* __restrict__ acc,
                       unsigned int* __restrict__ done, float* __restrict__ out) {
  int i = blockIdx.x * blockDim.x + threadIdx.x;
  int tid = threadIdx.x;
  double s = 0.0, n = 0.0;
  if (i < BB * VV) {
    int b = i / VV, v = i - b * VV;
    if (roi[i] != 0) {
      n = 1.0;
      const float* pb = prob + (size_t)b * CP * VV + v;
      const float* ab = Araw2 + (size_t)b * CF * VV + v;
      float inv = 1.0f / ab[CP * VV];
      float ls = 0.f;
      #pragma unroll
      for (int c = 0; c < CP; c++) ls += fabsf(pb[c * VV] - ab[c * VV] * inv);
      s = (double)ls;
    }
  }
  __shared__ double rs[256], rn[256];
  __shared__ bool amLast;
  rs[tid] = s; rn[tid] = n;
  __syncthreads();
  for (int d = 128; d > 0; d >>= 1) {
    if (tid < d) { rs[tid] += rs[tid + d]; rn[tid] += rn[tid + d]; }
    __syncthreads();
  }
  if (tid == 0) {
    atomicAdd(&acc[0], rs[0]);
    atomicAdd(&acc[1], rn[0]);
    __threadfence();
    unsigned int prev = atomicAdd(done, 1u);
    amLast = (prev == gridDim.x - 1);
  }
  __syncthreads();
  if (amLast && tid == 0) {
    __threadfence();
    double ss = acc[0], nn = acc[1];
    out[0] = (nn > 0.0) ? (float)(ss / nn) : 0.0f;
  }
}

extern "C" void kernel_launch(void* const* d_in, const int* in_sizes, int n_in,
                              void* d_out, int out_size, void* d_ws, size_t ws_size,
                              hipStream_t stream) {
  const float* preds = (const float*)d_in[0];
  const float* low   = (const float*)d_in[1];
  const float* high  = (const float*)d_in[2];
  const int*   roi   = (const int*)d_in[3];
  float* out = (float*)d_out;

  char* w = (char*)d_ws;
  size_t off = 0;
  auto alloc = [&](size_t bytes) -> void* {
    void* p = w + off;
    off += (bytes + 255) & ~(size_t)255;
    return p;
  };
  float* prob  = (float*)alloc((size_t)BB * CP * VV * 4);
  float* Araw1 = (float*)alloc((size_t)BB * CF * VV * 4);
  float* Araw2 = (float*)alloc((size_t)BB * CF * VV * 4);
  unsigned long long* ekey = (unsigned long long*)alloc((size_t)TT * EE * 8);
  int* mstU = (int*)alloc((size_t)TT * VV * 4);
  int* mstV = (int*)alloc((size_t)TT * VV * 4);
  int* ordG = (int*)alloc((size_t)TT * VV * 4);
  int* spG  = (int*)alloc((size_t)TT * VV * 4);
  int* lpG  = (int*)alloc((size_t)TT * (VV + 1) * 4);
  int* nlev = (int*)alloc((size_t)TT * 4);
  float* wvp = (float*)alloc((size_t)TT * VV * 4);
  double* acc = (double*)alloc(32);

  hipMemsetAsync(acc, 0, 32, stream);   // zeroes acc[0..1] and the done counter

  const int nSoft = (BB * VV + 1023) / 1024;   // 50 softmax side-car blocks
  k_edgekey<<<(TT * EE + 255) / 256, 256, 0, stream>>>(low, high, ekey);
  k_msttree<<<TT + nSoft, 1024, 0, stream>>>(ekey, mstU, mstV, ordG, spG, lpG, nlev, wvp, preds, prob);
  k_filter_pc<<<BB * CF, 1024, 0, stream>>>(prob,  Araw1, wvp, ordG, spG, lpG, nlev, 0);
  k_filter_pc<<<BB * CF, 1024, 0, stream>>>(Araw1, Araw2, wvp, ordG, spG, lpG, nlev, BB);
  k_loss<<<(BB * VV + 255) / 256, 256, 0, stream>>>(prob, Araw2, roi, acc,
      (unsigned int*)(acc + 2), out);
}

// Round 23
// 268.879 us; speedup vs baseline: 1.5617x; 1.0350x over previous
//
#include <hip/hip_runtime.h>

#define BB 8
#define CP 21
#define CF 22
#define CLOW 3
#define CHIGH 256
#define WW 80
#define VV 6400
#define EVERT 6320
#define EE 12640
#define TT 16
#define SIGMA_F 0.002f
#define ROOT 3240          // seed vertex for tour break / diameter search

#define NE (VV - 1)        // tree edges
#define NA (2 * NE)        // Euler arcs = 12798
#define NILA 0xFFFFu
#define NB 200             // ceil(NA/64) RMQ blocks

__device__ __forceinline__ void edge_uv(int e, int& u, int& v) {
  if (e < EVERT) { u = e; v = e + WW; }
  else { int e2 = e - EVERT; int r = e2 / (WW - 1); int c = e2 - r * (WW - 1); u = r * WW + c; v = u + 1; }
}

// ---------------- K2: edge keys (float64 cost, top-50-bits | edge idx) ----------------
__global__ void k_edgekey(const float* __restrict__ low, const float* __restrict__ high,
                          unsigned long long* __restrict__ ekey) {
  int i = blockIdx.x * blockDim.x + threadIdx.x;
  if (i >= TT * EE) return;
  int t = i / EE, e = i - t * EE;
  int u, v; edge_uv(e, u, v);
  double acc = 0.0;
  if (t < BB) {
    const float* emb = low + (size_t)t * CLOW * VV;
    for (int c = 0; c < CLOW; c++) { double d = (double)emb[c * VV + u] - (double)emb[c * VV + v]; acc += d * d; }
  } else {
    const float* emb = high + (size_t)(t - BB) * CHIGH * VV;
    for (int c = 0; c < CHIGH; c++) { double d = (double)emb[c * VV + u] - (double)emb[c * VV + v]; acc += d * d; }
  }
  unsigned long long bits = (unsigned long long)__double_as_longlong(acc);
  ekey[i] = (bits & ~0x3FFFULL) | (unsigned long long)e;
}

// ---------------- K3: FUSED: per-tree MST+rooting+weights (blocks 0..15) | softmax (blocks 16+) ----------------
__global__ __launch_bounds__(1024) void k_msttree(const unsigned long long* __restrict__ ekey,
    int* __restrict__ mstU, int* __restrict__ mstV,
    int* __restrict__ ordG, int* __restrict__ spG,
    int* __restrict__ lpG, int* __restrict__ nlevG, float* __restrict__ wvp,
    const float* __restrict__ preds, float* __restrict__ prob) {
  if (blockIdx.x >= TT) {
    // ---- softmax side-car ----
    int i = (blockIdx.x - TT) * 1024 + threadIdx.x;
    if (i < BB * VV) {
      int b = i / VV, v = i - b * VV;
      const float* p = preds + (size_t)b * CP * VV + v;
      float m = -1e30f;
      #pragma unroll
      for (int c = 0; c < CP; c++) m = fmaxf(m, p[c * VV]);
      float e[CP], s = 0.f;
      #pragma unroll
      for (int c = 0; c < CP; c++) { float x = expf(p[c * VV] - m); e[c] = x; s += x; }
      float inv = 1.f / s;
      float* o = prob + (size_t)b * CP * VV + v;
      #pragma unroll
      for (int c = 0; c < CP; c++) o[c * VV] = e[c] * inv;
    }
    return;
  }
  int t = blockIdx.x;
  const unsigned long long* key = ekey + (size_t)t * EE;
  int* mu = mstU + t * VV;
  int* mv = mstV + t * VV;
  int tid = threadIdx.x;
  const int nt = 1024;
  int lane = tid & 63, wid = tid >> 6;

  __shared__ alignas(16) char arena[152960];
  __shared__ int lasts, spackU, spackW, scenter, smaxd, changed, cnt, necnt, nrcnt;

  // ===== Phase 1 regions (Boruvka with root lists) =====
  int* comp = (int*)(arena + 0);                                   // int[VV]
  unsigned long long* bst = (unsigned long long*)(arena + 25600);  // u64[VV] -> 76800
  unsigned short* el0 = (unsigned short*)(arena + 76800);          // u16[EE] -> 102080
  unsigned short* el1 = (unsigned short*)(arena + 102080);         // u16[EE] -> 127360
  unsigned short* rl0 = (unsigned short*)(arena + 127360);         // u16[VV] -> 140160
  unsigned short* rl1 = (unsigned short*)(arena + 140160);         // u16[VV] -> 152960

  // ===== Phase 2 regions (Euler rooting; overlays Phase 1) =====
  char* buf = arena;
  int* deg = (int*)(buf + 0);
  int* off = (int*)(buf + 25600);
  unsigned short* adjA = (unsigned short*)(buf + 51208);
  unsigned short* succ = (unsigned short*)(buf + 102408);
  int* pk0 = (int*)(buf + 0);
  int* pk1 = (int*)(buf + 51208);
  unsigned short* r_a = (unsigned short*)(buf + 102408);
  short* H = (short*)(buf + 51208);
  unsigned short* depthR = (unsigned short*)(buf + 76808);
  unsigned short* firstK = (unsigned short*)(buf + 89608);
  short* prefmin = (short*)(buf + 0);
  short* sufmin  = (short*)(buf + 25600);
  unsigned short* distU = (unsigned short*)(buf + 76808);
  unsigned short* parentS = (unsigned short*)(buf + 76808);
  int* lev = (int*)(buf + 0);
  int* cur = (int*)(buf + 25604);
  unsigned short* ordS = (unsigned short*)(buf + 51208);
  unsigned short* posS = (unsigned short*)(buf + 64008);
  int* part = (int*)(buf + 128016);
  short* tbl = (short*)(buf + 128272);
  unsigned short* dbuf2 = (unsigned short*)(buf + 131472);

  auto blockScanEx = [&](int s) -> int {
    int x = s;
    #pragma unroll
    for (int d = 1; d < 64; d <<= 1) { int o = __shfl_up(x, d); if (lane >= d) x += o; }
    if (lane == 63) part[wid] = x;
    __syncthreads();
    if (wid == 0) {
      int y = (lane < 16) ? part[lane] : 0;
      #pragma unroll
      for (int d = 1; d < 16; d <<= 1) { int o = __shfl_up(y, d); if (lane >= d) y += o; }
      if (lane < 16) part[lane] = y;
    }
    __syncthreads();
    int base = (wid > 0) ? part[wid - 1] : 0;
    return base + (x - s);
  };

  // ============ PHASE 1: Boruvka (active-root lists, merged bst reset) ============
  for (int v = tid; v < VV; v += nt) { comp[v] = v; bst[v] = ~0ULL; }
  for (int e = tid; e < EE; e += nt) el0[e] = (unsigned short)e;
  for (int v = tid; v < VV; v += nt) rl0[v] = (unsigned short)v;
  if (tid == 0) cnt = 0;
  __syncthreads();
  {
    unsigned short *els = el0, *eld = el1;
    unsigned short *rls = rl0, *rld = rl1;
    int ecnt = EE, rcnt = VV;
    for (int round = 0; round < 48 && ecnt > 0; round++) {
      if (tid == 0) { changed = 0; necnt = 0; nrcnt = 0; }
      // edge scan (comp is fully compressed: depth 1)
      for (int j = tid; j < ecnt; j += nt) {
        int e = els[j];
        int u, v; edge_uv(e, u, v);
        int ru = comp[u], rv = comp[v];
        if (ru != rv) { unsigned long long k = key[e]; atomicMin(&bst[ru], k); atomicMin(&bst[rv], k); }
      }
      __syncthreads();
      // tgt per root-position, stored in dest edge buffer (dead until compaction)
      unsigned short* tgtJ = eld;
      for (int j = tid; j < rcnt; j += nt) {
        int c = rls[j];
        unsigned short tg = (unsigned short)NILA;
        unsigned long long k = bst[c];
        if (k != ~0ULL) {
          int e = (int)(k & 0x3FFFULL);
          int u, v; edge_uv(e, u, v);
          int cu = comp[u], cv = comp[v];
          tg = (unsigned short)((cu == c) ? cv : cu);
        }
        tgtJ[j] = tg;
      }
      __syncthreads();
      // hook
      for (int j = tid; j < rcnt; j += nt) {
        int c = rls[j];
        int o = tgtJ[j];
        if (o == (int)NILA) continue;
        unsigned long long k = bst[c];
        if (bst[o] == k && c < o) continue;  // mutual minimum edge: smaller id stays root
        comp[c] = o;
        int slot = atomicAdd(&cnt, 1);
        int e = (int)(k & 0x3FFFULL);
        int u, v; edge_uv(e, u, v);
        mu[slot] = u; mv[slot] = v;
        changed = 1;
      }
      __syncthreads();
      if (!changed) break;
      // barrier-free full path compression (depth back to 1)
      for (int v = tid; v < VV; v += nt) {
        int c = comp[v];
        int c2 = comp[c];
        if (c2 != c) {
          int r0 = c2;
          while (true) { int n = comp[r0]; if (n == r0) break; r0 = n; }
          comp[v] = r0;
        }
      }
      __syncthreads();
      // compact roots (+ reset their bst) and edges (tgtJ dead now)
      for (int j = tid; j < rcnt; j += nt) {
        int c = rls[j];
        if (comp[c] == c) { int s = atomicAdd(&nrcnt, 1); rld[s] = (unsigned short)c; bst[c] = ~0ULL; }
      }
      for (int j = tid; j < ecnt; j += nt) {
        int e = els[j];
        int u, v; edge_uv(e, u, v);
        if (comp[u] != comp[v]) { int s = atomicAdd(&necnt, 1); eld[s] = (unsigned short)e; }
      }
      __syncthreads();
      ecnt = necnt; rcnt = nrcnt;
      __syncthreads();   // all threads capture counts before next round's reset
      unsigned short* tp = els; els = eld; eld = tp;
      tp = rls; rls = rld; rld = tp;
    }
  }
  __threadfence();
  __syncthreads();

  // ============ PHASE 2: Euler-tour center rooting ============
  for (int v = tid; v < VV; v += nt) deg[v] = 0;
  __syncthreads();
  for (int e = tid; e < NE; e += nt) { atomicAdd(&deg[mu[e]], 1); atomicAdd(&deg[mv[e]], 1); }
  __syncthreads();
  {
    const int SCH = 7;
    int base = tid * SCH;
    int s = 0;
    #pragma unroll
    for (int k = 0; k < SCH; k++) { int v = base + k; if (v < VV) s += deg[v]; }
    int ex = blockScanEx(s);
    #pragma unroll
    for (int k = 0; k < SCH; k++) { int v = base + k; if (v < VV) { off[v] = ex; ex += deg[v]; } }
    if (tid == 1023) off[VV] = ex;
  }
  __syncthreads();
  for (int v = tid; v < VV; v += nt) deg[v] = off[v];
  __syncthreads();
  for (int e = tid; e < NE; e += nt) {
    int u = mu[e], v = mv[e];
    adjA[atomicAdd(&deg[u], 1)] = (unsigned short)(2 * e);
    adjA[atomicAdd(&deg[v], 1)] = (unsigned short)(2 * e + 1);
  }
  __syncthreads();
  for (int v = tid; v < VV; v += nt) {
    int b0 = off[v], dv = off[v + 1] - b0;
    for (int k = 0; k < dv; k++) {
      unsigned short a = adjA[b0 + k];
      unsigned short b = adjA[b0 + ((k + 1 == dv) ? 0 : k + 1)];
      succ[a ^ 1] = b;
    }
  }
  if (tid == 0) lasts = adjA[off[ROOT] + (off[ROOT + 1] - off[ROOT]) - 1] ^ 1;
  __syncthreads();
  if (tid == 0) succ[lasts] = (unsigned short)NILA;
  __syncthreads();
  for (int a = tid; a < NA; a += nt) {
    unsigned int n = succ[a];
    pk0[a] = ((n == NILA ? 0 : 1) << 16) | (int)n;
  }
  __syncthreads();
  {
    int* px = pk0;
    int* py = pk1;
    for (int rd = 0; rd < 14; rd++) {
      for (int a = tid; a < NA; a += nt) {
        int cur_ = px[a];
        int n = cur_ & 0xFFFF;
        if (n != (int)NILA) {
          int o = px[n];
          cur_ = (((cur_ >> 16) + (o >> 16)) << 16) | (o & 0xFFFF);
        }
        py[a] = cur_;
      }
      __syncthreads();
      int* tp = px; px = py; py = tp;
    }
    for (int a = tid; a < NA; a += nt) r_a[a] = (unsigned short)(pk0[a] >> 16);
  }
  __syncthreads();
  for (int a = tid; a < NA; a += nt) {
    int pa = NA - 1 - (int)r_a[a];
    int pb = NA - 1 - (int)r_a[a ^ 1];
    H[pa] = (pa < pb) ? (short)1 : (short)-1;
  }
  __syncthreads();
  {
    const int SCH = 13;
    int base = tid * SCH;
    int lim = base + SCH; if (lim > NA) lim = NA;
    int s = 0;
    for (int j = base; j < lim; j++) s += H[j];
    int run = blockScanEx(s);
    for (int j = base; j < lim; j++) { run += H[j]; H[j] = (short)run; }
  }
  __syncthreads();
  if (tid == 0) { spackU = 0; smaxd = 0; scenter = 0x7FFFFFFF; }
  __syncthreads();
  for (int a = tid; a < NA; a += nt) {
    int pa = NA - 1 - (int)r_a[a];
    int pb = NA - 1 - (int)r_a[a ^ 1];
    if (pa < pb) {
      int e = a >> 1;
      int head = (a & 1) ? mu[e] : mv[e];
      depthR[head] = (unsigned short)H[pa];
      firstK[head] = (unsigned short)(pa + 1);
    }
  }
  if (tid == 0) { depthR[ROOT] = 0; firstK[ROOT] = 0; }
  __syncthreads();
  {
    int loc = 0;
    for (int v = tid; v < VV; v += nt) { int p = ((int)depthR[v] << 13) | v; if (p > loc) loc = p; }
    #pragma unroll
    for (int d = 32; d > 0; d >>= 1) { int o = __shfl_down(loc, d); if (o > loc) loc = o; }
    if (lane == 0) atomicMax(&spackU, loc);
  }
  __syncthreads();
  {
    for (int seg = wid; seg < NB; seg += 16) {
      int p = seg * 64 + lane;
      int h = (p < NA) ? (int)H[p] : 32767;
      int hp = h;
      #pragma unroll
      for (int d = 1; d < 64; d <<= 1) { int o = __shfl_up(hp, d); if (lane >= d && o < hp) hp = o; }
      prefmin[p] = (short)hp;
      int hs = h;
      #pragma unroll
      for (int d = 1; d < 64; d <<= 1) { int o = __shfl_down(hs, d); if (lane + d < 64 && o < hs) hs = o; }
      sufmin[p] = (short)hs;
      if (lane == 0) tbl[seg] = (short)hs;
    }
  }
  __syncthreads();
  for (int k = 1; k < 8; k++) {
    short vv_ = 0;
    if (tid < NB) {
      int o = tid + (1 << (k - 1));
      short a = tbl[(k - 1) * NB + tid];
      short b2 = (o < NB) ? tbl[(k - 1) * NB + o] : (short)32767;
      vv_ = (a < b2) ? a : b2;
    }
    __syncthreads();
    if (tid < NB) tbl[k * NB + tid] = vv_;
    __syncthreads();
  }
  auto distq = [&](int K1, int K2) -> int {
    if (K1 == K2) return 0;
    int l = (K1 < K2 ? K1 : K2) - 1;
    int r = (K1 > K2 ? K1 : K2) - 1;
    int m = 32767;
    int l0 = l < 0 ? 0 : l;
    int bl = l0 >> 6, br = r >> 6;
    if (bl == br) {
      for (int p = l0; p <= r; p++) { int h = H[p]; if (h < m) m = h; }
    } else {
      int a = sufmin[l0], b2 = prefmin[r];
      m = a < b2 ? a : b2;
      int lo = bl + 1, hi = br - 1;
      if (lo <= hi) {
        int L = hi - lo + 1;
        int k = 31 - __builtin_clz(L);
        int c1 = tbl[k * NB + lo];
        int c2 = tbl[k * NB + hi - (1 << k) + 1];
        if (c1 < m) m = c1;
        if (c2 < m) m = c2;
      }
    }
    if (l < 0 && 0 < m) m = 0;
    int h1 = (K1 == 0) ? 0 : (int)H[K1 - 1];
    int h2 = (K2 == 0) ? 0 : (int)H[K2 - 1];
    return h1 + h2 - 2 * m;
  };
  int u = spackU & 0x1FFF;
  int Ku = firstK[u];
  if (tid == 0) spackW = 0;
  __syncthreads();
  {
    int loc = 0;
    for (int v = tid; v < VV; v += nt) {
      int d = distq(Ku, firstK[v]);
      distU[v] = (unsigned short)d;
      int p = (d << 13) | v;
      if (p > loc) loc = p;
    }
    #pragma unroll
    for (int d = 32; d > 0; d >>= 1) { int o = __shfl_down(loc, d); if (o > loc) loc = o; }
    if (lane == 0) atomicMax(&spackW, loc);
  }
  __syncthreads();
  int D = spackW >> 13;
  int w = spackW & 0x1FFF;
  int Kw = firstK[w];
  for (int v = tid; v < VV; v += nt) dbuf2[v] = (unsigned short)distq(Kw, firstK[v]);
  __syncthreads();
  {
    int half = D >> 1;
    for (int v = tid; v < VV; v += nt) {
      if ((int)distU[v] == half && (int)distU[v] + (int)dbuf2[v] == D) atomicMin(&scenter, v);
    }
  }
  __syncthreads();
  int cvert = (scenter == 0x7FFFFFFF) ? ROOT : scenter;
  int Kc = firstK[cvert];
  __syncthreads();
  {
    int loc = 0;
    for (int v = tid; v < VV; v += nt) {
      int d = distq(Kc, firstK[v]);
      dbuf2[v] = (unsigned short)d;
      if (d > loc) loc = d;
    }
    #pragma unroll
    for (int d = 32; d > 0; d >>= 1) { int o = __shfl_down(loc, d); if (o > loc) loc = o; }
    if (lane == 0) atomicMax(&smaxd, loc);
  }
  __syncthreads();
  int maxd = smaxd;
  int sTil = Kc;
  for (int a = tid; a < NA; a += nt) {
    int pa = NA - 1 - (int)r_a[a];
    int pb = NA - 1 - (int)r_a[a ^ 1];
    int pa2 = pa - sTil; if (pa2 < 0) pa2 += NA;
    int pb2 = pb - sTil; if (pb2 < 0) pb2 += NA;
    if (pa2 < pb2) {
      int e = a >> 1;
      int head = (a & 1) ? mu[e] : mv[e];
      int tail = (a & 1) ? mv[e] : mu[e];
      parentS[head] = (unsigned short)tail;
    }
  }
  if (tid == 0) parentS[cvert] = (unsigned short)cvert;
  __syncthreads();
  for (int d = tid; d <= VV; d += nt) lev[d] = 0;
  __syncthreads();
  for (int v = tid; v < VV; v += nt) atomicAdd(&lev[dbuf2[v]], 1);
  __syncthreads();
  {
    const int SCH = 7;
    int base = tid * SCH;
    int s = 0;
    #pragma unroll
    for (int k = 0; k < SCH; k++) { int d = base + k; if (d <= VV) s += lev[d]; }
    int ex = blockScanEx(s);
    #pragma unroll
    for (int k = 0; k < SCH; k++) {
      int d = base + k;
      if (d <= VV) {
        int st = ex;
        ex += lev[d];
        if (d < VV) cur[d] = st;
        lpG[t * (VV + 1) + d] = st;
      }
    }
  }
  __syncthreads();
  for (int v = tid; v < VV; v += nt) {
    int d = dbuf2[v];
    int slot = atomicAdd(&cur[d], 1);
    ordS[slot] = (unsigned short)v;
    posS[v] = (unsigned short)slot;
  }
  __syncthreads();
  for (int j = tid; j < VV; j += nt) {
    int v = ordS[j];
    int pv = parentS[v];
    ordG[t * VV + j] = v;
    spG[t * VV + j] = posS[pv];
    float wout;
    if (v == pv) {
      wout = 1.0f;  // root (filter transform special-cases pos 0)
    } else {
      int a = v < pv ? v : pv;
      int diff = v < pv ? pv - v : v - pv;
      int e;
      if (diff == WW) e = a;
      else { int r = a / WW, c = a - r * WW; e = EVERT + r * (WW - 1) + c; }
      unsigned long long k = key[e];
      double cost = __longlong_as_double((long long)(k & ~0x3FFFULL));
      wout = expf(-(float)cost / SIGMA_F);
    }
    wvp[t * VV + j] = wout;
  }
  if (tid == 0) nlevG[t] = maxd + 1;
}

// ---------------- K6: tree filter — 1024 threads; level-sweep up (wave 0), float2 doubling down ----------------
__global__ __launch_bounds__(1024) void k_filter_pc(const float* __restrict__ Fsrc, float* __restrict__ Araw,
    const float* __restrict__ wvp, const int* __restrict__ ordG, const int* __restrict__ spG,
    const int* __restrict__ lpG, const int* __restrict__ nlevG, int treeBase) {
  int blk = blockIdx.x;
  int b = blk / CF, ch = blk - b * CF;
  int t = treeBase + b;
  __shared__ alignas(16) char arena[140816];
  float2* ab0 = (float2*)(arena);
  float2* ab1 = (float2*)(arena + 51200);
  float*  S   = (float*)(arena + 51200);
  float*  w   = (float*)(arena + 76800);
  unsigned short* sp0 = (unsigned short*)(arena + 102400);
  unsigned short* sp1 = (unsigned short*)(arena + 115200);
  unsigned short* lpS = (unsigned short*)(arena + 128000);
  const int* ord = ordG + t * VV;
  const int* spt = spG + t * VV;
  const float* wsrc = wvp + t * VV;
  const int* lp = lpG + t * (VV + 1);
  int tid = threadIdx.x;
  const int nt = 1024;
  int NL = nlevG[t];
  for (int j = tid; j <= NL; j += nt) lpS[j] = (unsigned short)lp[j];
  const bool norm_in = (treeBase != 0);
  for (int j = tid; j < VV; j += nt) {
    sp0[j] = (unsigned short)spt[j];
    w[j] = wsrc[j];
    float val;
    if (ch < CP) {
      int v = ord[j];
      if (!norm_in) val = Fsrc[((size_t)b * CP + ch) * VV + v];
      else          val = Fsrc[((size_t)b * CF + ch) * VV + v] / Fsrc[((size_t)b * CF + CP) * VV + v];
    } else val = 1.0f;
    S[j] = val;
  }
  __syncthreads();
  if (tid < 64) {
    int s1 = lpS[NL];
    int s0 = lpS[NL - 1];
    for (int l = NL - 1; l >= 1; l--) {
      int s0n = (l > 1) ? (int)lpS[l - 1] : 0;
      for (int j = s0 + tid; j < s1; j += 64) {
        atomicAdd(&S[sp0[j]], w[j] * S[j]);
      }
      asm volatile("s_waitcnt lgkmcnt(0)" ::: "memory");
      __builtin_amdgcn_sched_barrier(0);
      s1 = s0; s0 = s0n;
    }
  }
  __syncthreads();
  for (int j = tid; j < VV; j += nt) {
    float wv = w[j];
    float a = (j == 0) ? 0.f : wv;
    float bv = (j == 0) ? S[0] : S[j] * (1.f - wv * wv);
    ab0[j] = make_float2(a, bv);
  }
  __syncthreads();
  int rounds = 0;
  { int d = 1; while (d < NL) { d <<= 1; rounds++; } }
  float2 *abs_ = ab0, *abd_ = ab1;
  unsigned short *ps_ = sp0, *pd_ = sp1;
  for (int r = 0; r < rounds; r++) {
    for (int j = tid; j < VV; j += nt) {
      float2 m = abs_[j];
      int p = ps_[j];
      float2 o = m;
      int pn = p;
      if (m.x != 0.f) {
        float2 mp = abs_[p];
        pn = ps_[p];
        o.x = m.x * mp.x;
        o.y = fmaf(m.x, mp.y, m.y);
      }
      abd_[j] = o;
      pd_[j] = (unsigned short)pn;
    }
    __syncthreads();
    float2* tf = abs_; abs_ = abd_; abd_ = tf;
    unsigned short* tu = ps_; ps_ = pd_; pd_ = tu;
  }
  float* Ob = Araw + ((size_t)b * CF + ch) * VV;
  for (int j = tid; j < VV; j += nt) Ob[ord[j]] = abs_[j].y;
}

// ---------------- K7: ROI-masked L1 loss with fused finalize (last-block-done) ----------------
__global__ void k_loss(const float* __restrict__ prob, const float* __restrict__ Araw2,
                       const int* __restrict__ roi, double* __restrict__ acc,
                       unsigned int* __restrict__ done, float* __restrict__ out) {
  int i = blockIdx.x * blockDim.x + threadIdx.x;
  int tid = threadIdx.x;
  double s = 0.0, n = 0.0;
  if (i < BB * VV) {
    int b = i / VV, v = i - b * VV;
    if (roi[i] != 0) {
      n = 1.0;
      const float* pb = prob + (size_t)b * CP * VV + v;
      const float* ab = Araw2 + (size_t)b * CF * VV + v;
      float inv = 1.0f / ab[CP * VV];
      float ls = 0.f;
      #pragma unroll
      for (int c = 0; c < CP; c++) ls += fabsf(pb[c * VV] - ab[c * VV] * inv);
      s = (double)ls;
    }
  }
  __shared__ double rs[256], rn[256];
  __shared__ bool amLast;
  rs[tid] = s; rn[tid] = n;
  __syncthreads();
  for (int d = 128; d > 0; d >>= 1) {
    if (tid < d) { rs[tid] += rs[tid + d]; rn[tid] += rn[tid + d]; }
    __syncthreads();
  }
  if (tid == 0) {
    atomicAdd(&acc[0], rs[0]);
    atomicAdd(&acc[1], rn[0]);
    __threadfence();
    unsigned int prev = atomicAdd(done, 1u);
    amLast = (prev == gridDim.x - 1);
  }
  __syncthreads();
  if (amLast && tid == 0) {
    __threadfence();
    double ss = acc[0], nn = acc[1];
    out[0] = (nn > 0.0) ? (float)(ss / nn) : 0.0f;
  }
}

extern "C" void kernel_launch(void* const* d_in, const int* in_sizes, int n_in,
                              void* d_out, int out_size, void* d_ws, size_t ws_size,
                              hipStream_t stream) {
  const float* preds = (const float*)d_in[0];
  const float* low   = (const float*)d_in[1];
  const float* high  = (const float*)d_in[2];
  const int*   roi   = (const int*)d_in[3];
  float* out = (float*)d_out;

  char* w = (char*)d_ws;
  size_t off = 0;
  auto alloc = [&](size_t bytes) -> void* {
    void* p = w + off;
    off += (bytes + 255) & ~(size_t)255;
    return p;
  };
  float* prob  = (float*)alloc((size_t)BB * CP * VV * 4);
  float* Araw1 = (float*)alloc((size_t)BB * CF * VV * 4);
  float* Araw2 = (float*)alloc((size_t)BB * CF * VV * 4);
  unsigned long long* ekey = (unsigned long long*)alloc((size_t)TT * EE * 8);
  int* mstU = (int*)alloc((size_t)TT * VV * 4);
  int* mstV = (int*)alloc((size_t)TT * VV * 4);
  int* ordG = (int*)alloc((size_t)TT * VV * 4);
  int* spG  = (int*)alloc((size_t)TT * VV * 4);
  int* lpG  = (int*)alloc((size_t)TT * (VV + 1) * 4);
  int* nlev = (int*)alloc((size_t)TT * 4);
  float* wvp = (float*)alloc((size_t)TT * VV * 4);
  double* acc = (double*)alloc(32);

  hipMemsetAsync(acc, 0, 32, stream);   // zeroes acc[0..1] and the done counter

  const int nSoft = (BB * VV + 1023) / 1024;   // 50 softmax side-car blocks
  k_edgekey<<<(TT * EE + 255) / 256, 256, 0, stream>>>(low, high, ekey);
  k_msttree<<<TT + nSoft, 1024, 0, stream>>>(ekey, mstU, mstV, ordG, spG, lpG, nlev, wvp, preds, prob);
  k_filter_pc<<<BB * CF, 1024, 0, stream>>>(prob,  Araw1, wvp, ordG, spG, lpG, nlev, 0);
  k_filter_pc<<<BB * CF, 1024, 0, stream>>>(Araw1, Araw2, wvp, ordG, spG, lpG, nlev, BB);
  k_loss<<<(BB * VV + 255) / 256, 256, 0, stream>>>(prob, Araw2, roi, acc,
      (unsigned int*)(acc + 2), out);
}

// Round 24
// 266.191 us; speedup vs baseline: 1.5774x; 1.0101x over previous
//
#include <hip/hip_runtime.h>

#define BB 8
#define CP 21
#define CF 22
#define CLOW 3
#define CHIGH 256
#define WW 80
#define VV 6400
#define EVERT 6320
#define EE 12640
#define TT 16
#define SIGMA_F 0.002f
#define ROOT 3240          // seed vertex for tour break / diameter search

#define NE (VV - 1)        // tree edges
#define NA (2 * NE)        // Euler arcs = 12798
#define NILA 0xFFFFu
#define NB 200             // ceil(NA/64) RMQ blocks

__device__ __forceinline__ void edge_uv(int e, int& u, int& v) {
  if (e < EVERT) { u = e; v = e + WW; }
  else { int e2 = e - EVERT; int r = e2 / (WW - 1); int c = e2 - r * (WW - 1); u = r * WW + c; v = u + 1; }
}

// ---------------- K2: edge keys (float64 cost, top-50-bits | edge idx) ----------------
__global__ void k_edgekey(const float* __restrict__ low, const float* __restrict__ high,
                          unsigned long long* __restrict__ ekey) {
  int i = blockIdx.x * blockDim.x + threadIdx.x;
  if (i >= TT * EE) return;
  int t = i / EE, e = i - t * EE;
  int u, v; edge_uv(e, u, v);
  double acc = 0.0;
  if (t < BB) {
    const float* emb = low + (size_t)t * CLOW * VV;
    for (int c = 0; c < CLOW; c++) { double d = (double)emb[c * VV + u] - (double)emb[c * VV + v]; acc += d * d; }
  } else {
    const float* emb = high + (size_t)(t - BB) * CHIGH * VV;
    for (int c = 0; c < CHIGH; c++) { double d = (double)emb[c * VV + u] - (double)emb[c * VV + v]; acc += d * d; }
  }
  unsigned long long bits = (unsigned long long)__double_as_longlong(acc);
  ekey[i] = (bits & ~0x3FFFULL) | (unsigned long long)e;
}

// ---------------- K3: FUSED: per-tree MST+rooting+weights (blocks 0..15) | softmax (blocks 16+) ----------------
__global__ __launch_bounds__(1024) void k_msttree(const unsigned long long* __restrict__ ekey,
    int* __restrict__ mstU, int* __restrict__ mstV,
    int* __restrict__ ordG, int* __restrict__ spG,
    int* __restrict__ lpG, int* __restrict__ nlevG, float* __restrict__ wvp,
    const float* __restrict__ preds, float* __restrict__ prob) {
  if (blockIdx.x >= TT) {
    // ---- softmax side-car ----
    int i = (blockIdx.x - TT) * 1024 + threadIdx.x;
    if (i < BB * VV) {
      int b = i / VV, v = i - b * VV;
      const float* p = preds + (size_t)b * CP * VV + v;
      float m = -1e30f;
      #pragma unroll
      for (int c = 0; c < CP; c++) m = fmaxf(m, p[c * VV]);
      float e[CP], s = 0.f;
      #pragma unroll
      for (int c = 0; c < CP; c++) { float x = expf(p[c * VV] - m); e[c] = x; s += x; }
      float inv = 1.f / s;
      float* o = prob + (size_t)b * CP * VV + v;
      #pragma unroll
      for (int c = 0; c < CP; c++) o[c * VV] = e[c] * inv;
    }
    return;
  }
  int t = blockIdx.x;
  const unsigned long long* key = ekey + (size_t)t * EE;
  int* mu = mstU + t * VV;
  int* mv = mstV + t * VV;
  int tid = threadIdx.x;
  const int nt = 1024;
  int lane = tid & 63, wid = tid >> 6;

  __shared__ alignas(16) char arena[152960];
  __shared__ int lasts, headS, spackU, spackW, scenter, smaxd, changed, cnt, necnt, nrcnt;

  // ===== Phase 1 regions (Boruvka with root lists) =====
  int* comp = (int*)(arena + 0);
  unsigned long long* bst = (unsigned long long*)(arena + 25600);
  unsigned short* el0 = (unsigned short*)(arena + 76800);
  unsigned short* el1 = (unsigned short*)(arena + 102080);
  unsigned short* rl0 = (unsigned short*)(arena + 127360);
  unsigned short* rl1 = (unsigned short*)(arena + 140160);

  // ===== Phase 2 regions (Euler rooting; overlays Phase 1) =====
  char* buf = arena;
  int* deg = (int*)(buf + 0);
  int* off = (int*)(buf + 25600);
  unsigned short* adjA = (unsigned short*)(buf + 51208);
  unsigned short* succ = (unsigned short*)(buf + 102408);
  // Helman-JaJa ranking regions
  unsigned short* subId = (unsigned short*)(buf + 0);      // u16[NA] (deg dead)
  unsigned short* locOf = (unsigned short*)(buf + 25600);  // u16[NA] (off dead)
  int* pkS0 = (int*)(buf + 51208);                         // int[1664] (adjA dead)
  int* pkS1 = (int*)(buf + 57864);                         // int[1664]
  unsigned short* r_a = (unsigned short*)(buf + 102408);   // overwrites succ after walks
  short* H = (short*)(buf + 51208);                        // pkS dead
  unsigned short* depthR = (unsigned short*)(buf + 76808);
  unsigned short* firstK = (unsigned short*)(buf + 89608);
  short* prefmin = (short*)(buf + 0);
  short* sufmin  = (short*)(buf + 25600);
  unsigned short* distU = (unsigned short*)(buf + 76808);
  unsigned short* parentS = (unsigned short*)(buf + 76808);
  int* lev = (int*)(buf + 0);
  int* cur = (int*)(buf + 25604);
  unsigned short* ordS = (unsigned short*)(buf + 51208);
  unsigned short* posS = (unsigned short*)(buf + 64008);
  int* part = (int*)(buf + 128016);
  short* tbl = (short*)(buf + 128272);
  unsigned short* dbuf2 = (unsigned short*)(buf + 131472);

  auto blockScanEx = [&](int s) -> int {
    int x = s;
    #pragma unroll
    for (int d = 1; d < 64; d <<= 1) { int o = __shfl_up(x, d); if (lane >= d) x += o; }
    if (lane == 63) part[wid] = x;
    __syncthreads();
    if (wid == 0) {
      int y = (lane < 16) ? part[lane] : 0;
      #pragma unroll
      for (int d = 1; d < 16; d <<= 1) { int o = __shfl_up(y, d); if (lane >= d) y += o; }
      if (lane < 16) part[lane] = y;
    }
    __syncthreads();
    int base = (wid > 0) ? part[wid - 1] : 0;
    return base + (x - s);
  };

  // ============ PHASE 1: Boruvka (active-root lists, merged bst reset) ============
  for (int v = tid; v < VV; v += nt) { comp[v] = v; bst[v] = ~0ULL; }
  for (int e = tid; e < EE; e += nt) el0[e] = (unsigned short)e;
  for (int v = tid; v < VV; v += nt) rl0[v] = (unsigned short)v;
  if (tid == 0) cnt = 0;
  __syncthreads();
  {
    unsigned short *els = el0, *eld = el1;
    unsigned short *rls = rl0, *rld = rl1;
    int ecnt = EE, rcnt = VV;
    for (int round = 0; round < 48 && ecnt > 0; round++) {
      if (tid == 0) { changed = 0; necnt = 0; nrcnt = 0; }
      for (int j = tid; j < ecnt; j += nt) {
        int e = els[j];
        int u, v; edge_uv(e, u, v);
        int ru = comp[u], rv = comp[v];
        if (ru != rv) { unsigned long long k = key[e]; atomicMin(&bst[ru], k); atomicMin(&bst[rv], k); }
      }
      __syncthreads();
      unsigned short* tgtJ = eld;
      for (int j = tid; j < rcnt; j += nt) {
        int c = rls[j];
        unsigned short tg = (unsigned short)NILA;
        unsigned long long k = bst[c];
        if (k != ~0ULL) {
          int e = (int)(k & 0x3FFFULL);
          int u, v; edge_uv(e, u, v);
          int cu = comp[u], cv = comp[v];
          tg = (unsigned short)((cu == c) ? cv : cu);
        }
        tgtJ[j] = tg;
      }
      __syncthreads();
      for (int j = tid; j < rcnt; j += nt) {
        int c = rls[j];
        int o = tgtJ[j];
        if (o == (int)NILA) continue;
        unsigned long long k = bst[c];
        if (bst[o] == k && c < o) continue;  // mutual minimum edge: smaller id stays root
        comp[c] = o;
        int slot = atomicAdd(&cnt, 1);
        int e = (int)(k & 0x3FFFULL);
        int u, v; edge_uv(e, u, v);
        mu[slot] = u; mv[slot] = v;
        changed = 1;
      }
      __syncthreads();
      if (!changed) break;
      for (int v = tid; v < VV; v += nt) {
        int c = comp[v];
        int c2 = comp[c];
        if (c2 != c) {
          int r0 = c2;
          while (true) { int n = comp[r0]; if (n == r0) break; r0 = n; }
          comp[v] = r0;
        }
      }
      __syncthreads();
      for (int j = tid; j < rcnt; j += nt) {
        int c = rls[j];
        if (comp[c] == c) { int s = atomicAdd(&nrcnt, 1); rld[s] = (unsigned short)c; bst[c] = ~0ULL; }
      }
      for (int j = tid; j < ecnt; j += nt) {
        int e = els[j];
        int u, v; edge_uv(e, u, v);
        if (comp[u] != comp[v]) { int s = atomicAdd(&necnt, 1); eld[s] = (unsigned short)e; }
      }
      __syncthreads();
      ecnt = necnt; rcnt = nrcnt;
      __syncthreads();
      unsigned short* tp = els; els = eld; eld = tp;
      tp = rls; rls = rld; rld = tp;
    }
  }
  __threadfence();
  __syncthreads();

  // ============ PHASE 2: Euler-tour center rooting ============
  for (int v = tid; v < VV; v += nt) deg[v] = 0;
  __syncthreads();
  for (int e = tid; e < NE; e += nt) { atomicAdd(&deg[mu[e]], 1); atomicAdd(&deg[mv[e]], 1); }
  __syncthreads();
  {
    const int SCH = 7;
    int base = tid * SCH;
    int s = 0;
    #pragma unroll
    for (int k = 0; k < SCH; k++) { int v = base + k; if (v < VV) s += deg[v]; }
    int ex = blockScanEx(s);
    #pragma unroll
    for (int k = 0; k < SCH; k++) { int v = base + k; if (v < VV) { off[v] = ex; ex += deg[v]; } }
    if (tid == 1023) off[VV] = ex;
  }
  __syncthreads();
  for (int v = tid; v < VV; v += nt) deg[v] = off[v];
  __syncthreads();
  for (int e = tid; e < NE; e += nt) {
    int u = mu[e], v = mv[e];
    adjA[atomicAdd(&deg[u], 1)] = (unsigned short)(2 * e);
    adjA[atomicAdd(&deg[v], 1)] = (unsigned short)(2 * e + 1);
  }
  __syncthreads();
  for (int v = tid; v < VV; v += nt) {
    int b0 = off[v], dv = off[v + 1] - b0;
    for (int k = 0; k < dv; k++) {
      unsigned short a = adjA[b0 + k];
      unsigned short b = adjA[b0 + ((k + 1 == dv) ? 0 : k + 1)];
      succ[a ^ 1] = b;
    }
  }
  if (tid == 0) {
    lasts = adjA[off[ROOT] + (off[ROOT + 1] - off[ROOT]) - 1] ^ 1;
    headS = adjA[off[ROOT]];           // first arc of the tour (succ[lasts] in the cycle)
  }
  __syncthreads();
  if (tid == 0) succ[lasts] = (unsigned short)NILA;
  __syncthreads();
  // ---- Helman-JaJa list ranking ----
  int headA = headS;
  int headExtra = (headA & 7) ? 1 : 0;
  int NS = 1600 + headExtra;
  for (int k = tid; k < NS; k += nt) {
    int a = (k < 1600) ? (k << 3) : headA;
    int off_ = 0;
    for (int step = 0; step < NA; step++) {
      subId[a] = (unsigned short)k;
      locOf[a] = (unsigned short)off_;
      off_++;
      int n = succ[a];
      if (n == (int)NILA) { pkS0[k] = (off_ << 16) | 0xFFFF; break; }
      if ((n & 7) == 0)   { pkS0[k] = (off_ << 16) | (n >> 3); break; }
      a = n;
    }
  }
  __syncthreads();
  int* pxF;
  {
    int* px = pkS0;
    int* py = pkS1;
    for (int rd = 0; rd < 11; rd++) {          // 2^11 >= 1601
      for (int k2 = tid; k2 < NS; k2 += nt) {
        int c = px[k2];
        int n = c & 0xFFFF;
        if (n != 0xFFFF) {
          int o = px[n];
          c = (((c >> 16) + (o >> 16)) << 16) | (o & 0xFFFF);
        }
        py[k2] = c;
      }
      __syncthreads();
      int* tp = px; px = py; py = tp;
    }
    pxF = px;                                   // ranks: total sublist length from k to end
  }
  // combine: r_a[a] = NA-1 - ((NA - totFrom(subId)) + locOf)   (writes over dead succ)
  for (int a = tid; a < NA; a += nt) {
    int k = subId[a];
    int totFrom = pxF[k] >> 16;
    int pos = (NA - totFrom) + (int)locOf[a];
    r_a[a] = (unsigned short)(NA - 1 - pos);
  }
  __syncthreads();
  // ---- tour values + shfl scan -> H ----
  for (int a = tid; a < NA; a += nt) {
    int pa = NA - 1 - (int)r_a[a];
    int pb = NA - 1 - (int)r_a[a ^ 1];
    H[pa] = (pa < pb) ? (short)1 : (short)-1;
  }
  __syncthreads();
  {
    const int SCH = 13;
    int base = tid * SCH;
    int lim = base + SCH; if (lim > NA) lim = NA;
    int s = 0;
    for (int j = base; j < lim; j++) s += H[j];
    int run = blockScanEx(s);
    for (int j = base; j < lim; j++) { run += H[j]; H[j] = (short)run; }
  }
  __syncthreads();
  if (tid == 0) { spackU = 0; smaxd = 0; scenter = 0x7FFFFFFF; }
  __syncthreads();
  for (int a = tid; a < NA; a += nt) {
    int pa = NA - 1 - (int)r_a[a];
    int pb = NA - 1 - (int)r_a[a ^ 1];
    if (pa < pb) {
      int e = a >> 1;
      int head = (a & 1) ? mu[e] : mv[e];
      depthR[head] = (unsigned short)H[pa];
      firstK[head] = (unsigned short)(pa + 1);
    }
  }
  if (tid == 0) { depthR[ROOT] = 0; firstK[ROOT] = 0; }
  __syncthreads();
  {
    int loc = 0;
    for (int v = tid; v < VV; v += nt) { int p = ((int)depthR[v] << 13) | v; if (p > loc) loc = p; }
    #pragma unroll
    for (int d = 32; d > 0; d >>= 1) { int o = __shfl_down(loc, d); if (o > loc) loc = o; }
    if (lane == 0) atomicMax(&spackU, loc);
  }
  __syncthreads();
  {
    for (int seg = wid; seg < NB; seg += 16) {
      int p = seg * 64 + lane;
      int h = (p < NA) ? (int)H[p] : 32767;
      int hp = h;
      #pragma unroll
      for (int d = 1; d < 64; d <<= 1) { int o = __shfl_up(hp, d); if (lane >= d && o < hp) hp = o; }
      prefmin[p] = (short)hp;
      int hs = h;
      #pragma unroll
      for (int d = 1; d < 64; d <<= 1) { int o = __shfl_down(hs, d); if (lane + d < 64 && o < hs) hs = o; }
      sufmin[p] = (short)hs;
      if (lane == 0) tbl[seg] = (short)hs;
    }
  }
  __syncthreads();
  for (int k = 1; k < 8; k++) {
    short vv_ = 0;
    if (tid < NB) {
      int o = tid + (1 << (k - 1));
      short a = tbl[(k - 1) * NB + tid];
      short b2 = (o < NB) ? tbl[(k - 1) * NB + o] : (short)32767;
      vv_ = (a < b2) ? a : b2;
    }
    __syncthreads();
    if (tid < NB) tbl[k * NB + tid] = vv_;
    __syncthreads();
  }
  auto distq = [&](int K1, int K2) -> int {
    if (K1 == K2) return 0;
    int l = (K1 < K2 ? K1 : K2) - 1;
    int r = (K1 > K2 ? K1 : K2) - 1;
    int m = 32767;
    int l0 = l < 0 ? 0 : l;
    int bl = l0 >> 6, br = r >> 6;
    if (bl == br) {
      for (int p = l0; p <= r; p++) { int h = H[p]; if (h < m) m = h; }
    } else {
      int a = sufmin[l0], b2 = prefmin[r];
      m = a < b2 ? a : b2;
      int lo = bl + 1, hi = br - 1;
      if (lo <= hi) {
        int L = hi - lo + 1;
        int k = 31 - __builtin_clz(L);
        int c1 = tbl[k * NB + lo];
        int c2 = tbl[k * NB + hi - (1 << k) + 1];
        if (c1 < m) m = c1;
        if (c2 < m) m = c2;
      }
    }
    if (l < 0 && 0 < m) m = 0;
    int h1 = (K1 == 0) ? 0 : (int)H[K1 - 1];
    int h2 = (K2 == 0) ? 0 : (int)H[K2 - 1];
    return h1 + h2 - 2 * m;
  };
  int u = spackU & 0x1FFF;
  int Ku = firstK[u];
  if (tid == 0) spackW = 0;
  __syncthreads();
  {
    int loc = 0;
    for (int v = tid; v < VV; v += nt) {
      int d = distq(Ku, firstK[v]);
      distU[v] = (unsigned short)d;
      int p = (d << 13) | v;
      if (p > loc) loc = p;
    }
    #pragma unroll
    for (int d = 32; d > 0; d >>= 1) { int o = __shfl_down(loc, d); if (o > loc) loc = o; }
    if (lane == 0) atomicMax(&spackW, loc);
  }
  __syncthreads();
  int D = spackW >> 13;
  int w = spackW & 0x1FFF;
  int Kw = firstK[w];
  for (int v = tid; v < VV; v += nt) dbuf2[v] = (unsigned short)distq(Kw, firstK[v]);
  __syncthreads();
  {
    int half = D >> 1;
    for (int v = tid; v < VV; v += nt) {
      if ((int)distU[v] == half && (int)distU[v] + (int)dbuf2[v] == D) atomicMin(&scenter, v);
    }
  }
  __syncthreads();
  int cvert = (scenter == 0x7FFFFFFF) ? ROOT : scenter;
  int Kc = firstK[cvert];
  __syncthreads();
  {
    int loc = 0;
    for (int v = tid; v < VV; v += nt) {
      int d = distq(Kc, firstK[v]);
      dbuf2[v] = (unsigned short)d;
      if (d > loc) loc = d;
    }
    #pragma unroll
    for (int d = 32; d > 0; d >>= 1) { int o = __shfl_down(loc, d); if (o > loc) loc = o; }
    if (lane == 0) atomicMax(&smaxd, loc);
  }
  __syncthreads();
  int maxd = smaxd;
  int sTil = Kc;
  for (int a = tid; a < NA; a += nt) {
    int pa = NA - 1 - (int)r_a[a];
    int pb = NA - 1 - (int)r_a[a ^ 1];
    int pa2 = pa - sTil; if (pa2 < 0) pa2 += NA;
    int pb2 = pb - sTil; if (pb2 < 0) pb2 += NA;
    if (pa2 < pb2) {
      int e = a >> 1;
      int head = (a & 1) ? mu[e] : mv[e];
      int tail = (a & 1) ? mv[e] : mu[e];
      parentS[head] = (unsigned short)tail;
    }
  }
  if (tid == 0) parentS[cvert] = (unsigned short)cvert;
  __syncthreads();
  for (int d = tid; d <= VV; d += nt) lev[d] = 0;
  __syncthreads();
  for (int v = tid; v < VV; v += nt) atomicAdd(&lev[dbuf2[v]], 1);
  __syncthreads();
  {
    const int SCH = 7;
    int base = tid * SCH;
    int s = 0;
    #pragma unroll
    for (int k = 0; k < SCH; k++) { int d = base + k; if (d <= VV) s += lev[d]; }
    int ex = blockScanEx(s);
    #pragma unroll
    for (int k = 0; k < SCH; k++) {
      int d = base + k;
      if (d <= VV) {
        int st = ex;
        ex += lev[d];
        if (d < VV) cur[d] = st;
        lpG[t * (VV + 1) + d] = st;
      }
    }
  }
  __syncthreads();
  for (int v = tid; v < VV; v += nt) {
    int d = dbuf2[v];
    int slot = atomicAdd(&cur[d], 1);
    ordS[slot] = (unsigned short)v;
    posS[v] = (unsigned short)slot;
  }
  __syncthreads();
  for (int j = tid; j < VV; j += nt) {
    int v = ordS[j];
    int pv = parentS[v];
    ordG[t * VV + j] = v;
    spG[t * VV + j] = posS[pv];
    float wout;
    if (v == pv) {
      wout = 1.0f;  // root (filter transform special-cases pos 0)
    } else {
      int a = v < pv ? v : pv;
      int diff = v < pv ? pv - v : v - pv;
      int e;
      if (diff == WW) e = a;
      else { int r = a / WW, c = a - r * WW; e = EVERT + r * (WW - 1) + c; }
      unsigned long long k = key[e];
      double cost = __longlong_as_double((long long)(k & ~0x3FFFULL));
      wout = expf(-(float)cost / SIGMA_F);
    }
    wvp[t * VV + j] = wout;
  }
  if (tid == 0) nlevG[t] = maxd + 1;
}

// ---------------- K6: tree filter — 1024 threads; level-sweep up (wave 0), float2 doubling down ----------------
__global__ __launch_bounds__(1024) void k_filter_pc(const float* __restrict__ Fsrc, float* __restrict__ Araw,
    const float* __restrict__ wvp, const int* __restrict__ ordG, const int* __restrict__ spG,
    const int* __restrict__ lpG, const int* __restrict__ nlevG, int treeBase) {
  int blk = blockIdx.x;
  int b = blk / CF, ch = blk - b * CF;
  int t = treeBase + b;
  __shared__ alignas(16) char arena[140816];
  float2* ab0 = (float2*)(arena);
  float2* ab1 = (float2*)(arena + 51200);
  float*  S   = (float*)(arena + 51200);
  float*  w   = (float*)(arena + 76800);
  unsigned short* sp0 = (unsigned short*)(arena + 102400);
  unsigned short* sp1 = (unsigned short*)(arena + 115200);
  unsigned short* lpS = (unsigned short*)(arena + 128000);
  const int* ord = ordG + t * VV;
  const int* spt = spG + t * VV;
  const float* wsrc = wvp + t * VV;
  const int* lp = lpG + t * (VV + 1);
  int tid = threadIdx.x;
  const int nt = 1024;
  int NL = nlevG[t];
  for (int j = tid; j <= NL; j += nt) lpS[j] = (unsigned short)lp[j];
  const bool norm_in = (treeBase != 0);
  for (int j = tid; j < VV; j += nt) {
    sp0[j] = (unsigned short)spt[j];
    w[j] = wsrc[j];
    float val;
    if (ch < CP) {
      int v = ord[j];
      if (!norm_in) val = Fsrc[((size_t)b * CP + ch) * VV + v];
      else          val = Fsrc[((size_t)b * CF + ch) * VV + v] / Fsrc[((size_t)b * CF + CP) * VV + v];
    } else val = 1.0f;
    S[j] = val;
  }
  __syncthreads();
  if (tid < 64) {
    int s1 = lpS[NL];
    int s0 = lpS[NL - 1];
    for (int l = NL - 1; l >= 1; l--) {
      int s0n = (l > 1) ? (int)lpS[l - 1] : 0;
      for (int j = s0 + tid; j < s1; j += 64) {
        atomicAdd(&S[sp0[j]], w[j] * S[j]);
      }
      asm volatile("s_waitcnt lgkmcnt(0)" ::: "memory");
      __builtin_amdgcn_sched_barrier(0);
      s1 = s0; s0 = s0n;
    }
  }
  __syncthreads();
  for (int j = tid; j < VV; j += nt) {
    float wv = w[j];
    float a = (j == 0) ? 0.f : wv;
    float bv = (j == 0) ? S[0] : S[j] * (1.f - wv * wv);
    ab0[j] = make_float2(a, bv);
  }
  __syncthreads();
  int rounds = 0;
  { int d = 1; while (d < NL) { d <<= 1; rounds++; } }
  float2 *abs_ = ab0, *abd_ = ab1;
  unsigned short *ps_ = sp0, *pd_ = sp1;
  for (int r = 0; r < rounds; r++) {
    for (int j = tid; j < VV; j += nt) {
      float2 m = abs_[j];
      int p = ps_[j];
      float2 o = m;
      int pn = p;
      if (m.x != 0.f) {
        float2 mp = abs_[p];
        pn = ps_[p];
        o.x = m.x * mp.x;
        o.y = fmaf(m.x, mp.y, m.y);
      }
      abd_[j] = o;
      pd_[j] = (unsigned short)pn;
    }
    __syncthreads();
    float2* tf = abs_; abs_ = abd_; abd_ = tf;
    unsigned short* tu = ps_; ps_ = pd_; pd_ = tu;
  }
  float* Ob = Araw + ((size_t)b * CF + ch) * VV;
  for (int j = tid; j < VV; j += nt) Ob[ord[j]] = abs_[j].y;
}

// ---------------- K7: ROI-masked L1 loss with fused finalize (last-block-done) ----------------
__global__ void k_loss(const float* __restrict__ prob, const float* __restrict__ Araw2,
                       const int* __restrict__ roi, double* __restrict__ acc,
                       unsigned int* __restrict__ done, float* __restrict__ out) {
  int i = blockIdx.x * blockDim.x + threadIdx.x;
  int tid = threadIdx.x;
  double s = 0.0, n = 0.0;
  if (i < BB * VV) {
    int b = i / VV, v = i - b * VV;
    if (roi[i] != 0) {
      n = 1.0;
      const float* pb = prob + (size_t)b * CP * VV + v;
      const float* ab = Araw2 + (size_t)b * CF * VV + v;
      float inv = 1.0f / ab[CP * VV];
      float ls = 0.f;
      #pragma unroll
      for (int c = 0; c < CP; c++) ls += fabsf(pb[c * VV] - ab[c * VV] * inv);
      s = (double)ls;
    }
  }
  __shared__ double rs[256], rn[256];
  __shared__ bool amLast;
  rs[tid] = s; rn[tid] = n;
  __syncthreads();
  for (int d = 128; d > 0; d >>= 1) {
    if (tid < d) { rs[tid] += rs[tid + d]; rn[tid] += rn[tid + d]; }
    __syncthreads();
  }
  if (tid == 0) {
    atomicAdd(&acc[0], rs[0]);
    atomicAdd(&acc[1], rn[0]);
    __threadfence();
    unsigned int prev = atomicAdd(done, 1u);
    amLast = (prev == gridDim.x - 1);
  }
  __syncthreads();
  if (amLast && tid == 0) {
    __threadfence();
    double ss = acc[0], nn = acc[1];
    out[0] = (nn > 0.0) ? (float)(ss / nn) : 0.0f;
  }
}

extern "C" void kernel_launch(void* const* d_in, const int* in_sizes, int n_in,
                              void* d_out, int out_size, void* d_ws, size_t ws_size,
                              hipStream_t stream) {
  const float* preds = (const float*)d_in[0];
  const float* low   = (const float*)d_in[1];
  const float* high  = (const float*)d_in[2];
  const int*   roi   = (const int*)d_in[3];
  float* out = (float*)d_out;

  char* w = (char*)d_ws;
  size_t off = 0;
  auto alloc = [&](size_t bytes) -> void* {
    void* p = w + off;
    off += (bytes + 255) & ~(size_t)255;
    return p;
  };
  float* prob  = (float*)alloc((size_t)BB * CP * VV * 4);
  float* Araw1 = (float*)alloc((size_t)BB * CF * VV * 4);
  float* Araw2 = (float*)alloc((size_t)BB * CF * VV * 4);
  unsigned long long* ekey = (unsigned long long*)alloc((size_t)TT * EE * 8);
  int* mstU = (int*)alloc((size_t)TT * VV * 4);
  int* mstV = (int*)alloc((size_t)TT * VV * 4);
  int* ordG = (int*)alloc((size_t)TT * VV * 4);
  int* spG  = (int*)alloc((size_t)TT * VV * 4);
  int* lpG  = (int*)alloc((size_t)TT * (VV + 1) * 4);
  int* nlev = (int*)alloc((size_t)TT * 4);
  float* wvp = (float*)alloc((size_t)TT * VV * 4);
  double* acc = (double*)alloc(32);

  hipMemsetAsync(acc, 0, 32, stream);   // zeroes acc[0..1] and the done counter

  const int nSoft = (BB * VV + 1023) / 1024;   // 50 softmax side-car blocks
  k_edgekey<<<(TT * EE + 255) / 256, 256, 0, stream>>>(low, high, ekey);
  k_msttree<<<TT + nSoft, 1024, 0, stream>>>(ekey, mstU, mstV, ordG, spG, lpG, nlev, wvp, preds, prob);
  k_filter_pc<<<BB * CF, 1024, 0, stream>>>(prob,  Araw1, wvp, ordG, spG, lpG, nlev, 0);
  k_filter_pc<<<BB * CF, 1024, 0, stream>>>(Araw1, Araw2, wvp, ordG, spG, lpG, nlev, BB);
  k_loss<<<(BB * VV + 255) / 256, 256, 0, stream>>>(prob, Araw2, roi, acc,
      (unsigned int*)(acc + 2), out);
}

// Round 25
// 264.902 us; speedup vs baseline: 1.5851x; 1.0049x over previous
//
#include <hip/hip_runtime.h>

#define BB 8
#define CP 21
#define CF 22
#define CLOW 3
#define CHIGH 256
#define WW 80
#define VV 6400
#define EVERT 6320
#define EE 12640
#define TT 16
#define SIGMA_F 0.002f
#define ROOT 3240          // seed vertex for tour break / diameter search

#define NE (VV - 1)        // tree edges
#define NA (2 * NE)        // Euler arcs = 12798
#define NILA 0xFFFFu
#define NB 200             // ceil(NA/64) RMQ blocks

__device__ __forceinline__ void edge_uv(int e, int& u, int& v) {
  if (e < EVERT) { u = e; v = e + WW; }
  else { int e2 = e - EVERT; int r = e2 / (WW - 1); int c = e2 - r * (WW - 1); u = r * WW + c; v = u + 1; }
}

// ---------------- K2: edge keys (float64 cost, top-50-bits | edge idx) ----------------
__global__ void k_edgekey(const float* __restrict__ low, const float* __restrict__ high,
                          unsigned long long* __restrict__ ekey) {
  int i = blockIdx.x * blockDim.x + threadIdx.x;
  if (i >= TT * EE) return;
  int t = i / EE, e = i - t * EE;
  int u, v; edge_uv(e, u, v);
  double acc = 0.0;
  if (t < BB) {
    const float* emb = low + (size_t)t * CLOW * VV;
    for (int c = 0; c < CLOW; c++) { double d = (double)emb[c * VV + u] - (double)emb[c * VV + v]; acc += d * d; }
  } else {
    const float* emb = high + (size_t)(t - BB) * CHIGH * VV;
    for (int c = 0; c < CHIGH; c++) { double d = (double)emb[c * VV + u] - (double)emb[c * VV + v]; acc += d * d; }
  }
  unsigned long long bits = (unsigned long long)__double_as_longlong(acc);
  ekey[i] = (bits & ~0x3FFFULL) | (unsigned long long)e;
}

// ---------------- K3: FUSED: per-tree MST+rooting+weights (blocks 0..15) | softmax (blocks 16+) ----------------
__global__ __launch_bounds__(1024) void k_msttree(const unsigned long long* __restrict__ ekey,
    int* __restrict__ mstU, int* __restrict__ mstV,
    int* __restrict__ ordG, int* __restrict__ spG,
    int* __restrict__ lpG, int* __restrict__ nlevG, float* __restrict__ wvp,
    const float* __restrict__ preds, float* __restrict__ prob) {
  if (blockIdx.x >= TT) {
    // ---- softmax side-car ----
    int i = (blockIdx.x - TT) * 1024 + threadIdx.x;
    if (i < BB * VV) {
      int b = i / VV, v = i - b * VV;
      const float* p = preds + (size_t)b * CP * VV + v;
      float m = -1e30f;
      #pragma unroll
      for (int c = 0; c < CP; c++) m = fmaxf(m, p[c * VV]);
      float e[CP], s = 0.f;
      #pragma unroll
      for (int c = 0; c < CP; c++) { float x = expf(p[c * VV] - m); e[c] = x; s += x; }
      float inv = 1.f / s;
      float* o = prob + (size_t)b * CP * VV + v;
      #pragma unroll
      for (int c = 0; c < CP; c++) o[c * VV] = e[c] * inv;
    }
    return;
  }
  int t = blockIdx.x;
  const unsigned long long* key = ekey + (size_t)t * EE;
  int* mu = mstU + t * VV;
  int* mv = mstV + t * VV;
  int tid = threadIdx.x;
  const int nt = 1024;
  int lane = tid & 63, wid = tid >> 6;

  __shared__ alignas(16) char arena[152960];
  __shared__ int lasts, headS, spackU, spackW, scenter, smaxd, changed, cnt, necnt, nrcnt;

  // ===== Phase 1 regions (Boruvka with root lists) =====
  int* comp = (int*)(arena + 0);
  unsigned long long* bst = (unsigned long long*)(arena + 25600);
  unsigned short* el0 = (unsigned short*)(arena + 76800);
  unsigned short* el1 = (unsigned short*)(arena + 102080);
  unsigned short* rl0 = (unsigned short*)(arena + 127360);
  unsigned short* rl1 = (unsigned short*)(arena + 140160);

  // ===== Phase 2 regions (Euler rooting; overlays Phase 1) =====
  char* buf = arena;
  int* deg = (int*)(buf + 0);
  int* off = (int*)(buf + 25600);
  unsigned short* adjA = (unsigned short*)(buf + 51208);
  unsigned short* succ = (unsigned short*)(buf + 102408);
  // Helman-JaJa ranking regions
  unsigned short* subId = (unsigned short*)(buf + 0);      // u16[NA] (deg dead)
  unsigned short* locOf = (unsigned short*)(buf + 25600);  // u16[NA] (off dead)
  int* pkS0 = (int*)(buf + 51208);                         // int[1664] (adjA dead)
  int* pkS1 = (int*)(buf + 57864);                         // int[1664]
  unsigned short* r_a = (unsigned short*)(buf + 102408);   // overwrites succ after walks
  short* H = (short*)(buf + 51208);                        // pkS dead
  unsigned short* depthR = (unsigned short*)(buf + 76808);
  unsigned short* firstK = (unsigned short*)(buf + 89608);
  short* prefmin = (short*)(buf + 0);
  short* sufmin  = (short*)(buf + 25600);
  unsigned short* distU = (unsigned short*)(buf + 76808);
  unsigned short* parentS = (unsigned short*)(buf + 76808);
  int* lev = (int*)(buf + 0);
  int* cur = (int*)(buf + 25604);
  unsigned short* ordS = (unsigned short*)(buf + 51208);
  unsigned short* posS = (unsigned short*)(buf + 64008);
  int* part = (int*)(buf + 128016);
  short* tbl = (short*)(buf + 128272);
  unsigned short* dbuf2 = (unsigned short*)(buf + 131472);

  auto blockScanEx = [&](int s) -> int {
    int x = s;
    #pragma unroll
    for (int d = 1; d < 64; d <<= 1) { int o = __shfl_up(x, d); if (lane >= d) x += o; }
    if (lane == 63) part[wid] = x;
    __syncthreads();
    if (wid == 0) {
      int y = (lane < 16) ? part[lane] : 0;
      #pragma unroll
      for (int d = 1; d < 16; d <<= 1) { int o = __shfl_up(y, d); if (lane >= d) y += o; }
      if (lane < 16) part[lane] = y;
    }
    __syncthreads();
    int base = (wid > 0) ? part[wid - 1] : 0;
    return base + (x - s);
  };

  // ============ PHASE 1: Boruvka (active-root lists, merged bst reset, early exit) ============
  for (int v = tid; v < VV; v += nt) { comp[v] = v; bst[v] = ~0ULL; }
  for (int e = tid; e < EE; e += nt) el0[e] = (unsigned short)e;
  for (int v = tid; v < VV; v += nt) rl0[v] = (unsigned short)v;
  if (tid == 0) cnt = 0;
  __syncthreads();
  {
    unsigned short *els = el0, *eld = el1;
    unsigned short *rls = rl0, *rld = rl1;
    int ecnt = EE, rcnt = VV;
    for (int round = 0; round < 48 && ecnt > 0; round++) {
      if (tid == 0) { changed = 0; necnt = 0; nrcnt = 0; }
      for (int j = tid; j < ecnt; j += nt) {
        int e = els[j];
        int u, v; edge_uv(e, u, v);
        int ru = comp[u], rv = comp[v];
        if (ru != rv) { unsigned long long k = key[e]; atomicMin(&bst[ru], k); atomicMin(&bst[rv], k); }
      }
      __syncthreads();
      unsigned short* tgtJ = eld;
      for (int j = tid; j < rcnt; j += nt) {
        int c = rls[j];
        unsigned short tg = (unsigned short)NILA;
        unsigned long long k = bst[c];
        if (k != ~0ULL) {
          int e = (int)(k & 0x3FFFULL);
          int u, v; edge_uv(e, u, v);
          int cu = comp[u], cv = comp[v];
          tg = (unsigned short)((cu == c) ? cv : cu);
        }
        tgtJ[j] = tg;
      }
      __syncthreads();
      for (int j = tid; j < rcnt; j += nt) {
        int c = rls[j];
        int o = tgtJ[j];
        if (o == (int)NILA) continue;
        unsigned long long k = bst[c];
        if (bst[o] == k && c < o) continue;  // mutual minimum edge: smaller id stays root
        comp[c] = o;
        int slot = atomicAdd(&cnt, 1);
        int e = (int)(k & 0x3FFFULL);
        int u, v; edge_uv(e, u, v);
        mu[slot] = u; mv[slot] = v;
        changed = 1;
      }
      __syncthreads();
      if (!changed) break;
      if (cnt >= NE) break;   // MST complete: skip final compression/compaction
      for (int v = tid; v < VV; v += nt) {
        int c = comp[v];
        int c2 = comp[c];
        if (c2 != c) {
          int r0 = c2;
          while (true) { int n = comp[r0]; if (n == r0) break; r0 = n; }
          comp[v] = r0;
        }
      }
      __syncthreads();
      for (int j = tid; j < rcnt; j += nt) {
        int c = rls[j];
        if (comp[c] == c) { int s = atomicAdd(&nrcnt, 1); rld[s] = (unsigned short)c; bst[c] = ~0ULL; }
      }
      for (int j = tid; j < ecnt; j += nt) {
        int e = els[j];
        int u, v; edge_uv(e, u, v);
        if (comp[u] != comp[v]) { int s = atomicAdd(&necnt, 1); eld[s] = (unsigned short)e; }
      }
      __syncthreads();
      ecnt = necnt; rcnt = nrcnt;
      __syncthreads();
      unsigned short* tp = els; els = eld; eld = tp;
      tp = rls; rls = rld; rld = tp;
    }
  }
  __threadfence();
  __syncthreads();

  // ============ PHASE 2: Euler-tour center rooting ============
  for (int v = tid; v < VV; v += nt) deg[v] = 0;
  __syncthreads();
  for (int e = tid; e < NE; e += nt) { atomicAdd(&deg[mu[e]], 1); atomicAdd(&deg[mv[e]], 1); }
  __syncthreads();
  {
    const int SCH = 7;
    int base = tid * SCH;
    int s = 0;
    #pragma unroll
    for (int k = 0; k < SCH; k++) { int v = base + k; if (v < VV) s += deg[v]; }
    int ex = blockScanEx(s);
    #pragma unroll
    for (int k = 0; k < SCH; k++) {
      int v = base + k;
      if (v < VV) { int dv = deg[v]; off[v] = ex; deg[v] = ex; ex += dv; }  // cursor merged
    }
    if (tid == 1023) off[VV] = ex;
  }
  __syncthreads();
  for (int e = tid; e < NE; e += nt) {
    int u = mu[e], v = mv[e];
    adjA[atomicAdd(&deg[u], 1)] = (unsigned short)(2 * e);
    adjA[atomicAdd(&deg[v], 1)] = (unsigned short)(2 * e + 1);
  }
  __syncthreads();
  for (int v = tid; v < VV; v += nt) {
    int b0 = off[v], dv = off[v + 1] - b0;
    for (int k = 0; k < dv; k++) {
      unsigned short a = adjA[b0 + k];
      unsigned short b = adjA[b0 + ((k + 1 == dv) ? 0 : k + 1)];
      succ[a ^ 1] = b;
    }
  }
  __syncthreads();
  if (tid == 0) {
    lasts = adjA[off[ROOT] + (off[ROOT + 1] - off[ROOT]) - 1] ^ 1;
    headS = adjA[off[ROOT]];
    succ[lasts] = (unsigned short)NILA;    // merged with lasts compute (one barrier saved)
  }
  __syncthreads();
  // ---- Helman-JaJa list ranking ----
  int headA = headS;
  int headExtra = (headA & 7) ? 1 : 0;
  int NS = 1600 + headExtra;
  for (int k = tid; k < NS; k += nt) {
    int a = (k < 1600) ? (k << 3) : headA;
    int off_ = 0;
    for (int step = 0; step < NA; step++) {
      subId[a] = (unsigned short)k;
      locOf[a] = (unsigned short)off_;
      off_++;
      int n = succ[a];
      if (n == (int)NILA) { pkS0[k] = (off_ << 16) | 0xFFFF; break; }
      if ((n & 7) == 0)   { pkS0[k] = (off_ << 16) | (n >> 3); break; }
      a = n;
    }
  }
  __syncthreads();
  int* pxF;
  {
    int* px = pkS0;
    int* py = pkS1;
    for (int rd = 0; rd < 11; rd++) {          // 2^11 >= 1601
      for (int k2 = tid; k2 < NS; k2 += nt) {
        int c = px[k2];
        int n = c & 0xFFFF;
        if (n != 0xFFFF) {
          int o = px[n];
          c = (((c >> 16) + (o >> 16)) << 16) | (o & 0xFFFF);
        }
        py[k2] = c;
      }
      __syncthreads();
      int* tp = px; px = py; py = tp;
    }
    pxF = px;
  }
  for (int a = tid; a < NA; a += nt) {
    int k = subId[a];
    int totFrom = pxF[k] >> 16;
    int pos = (NA - totFrom) + (int)locOf[a];
    r_a[a] = (unsigned short)(NA - 1 - pos);
  }
  __syncthreads();
  // ---- tour values + shfl scan -> H ----
  for (int a = tid; a < NA; a += nt) {
    int pa = NA - 1 - (int)r_a[a];
    int pb = NA - 1 - (int)r_a[a ^ 1];
    H[pa] = (pa < pb) ? (short)1 : (short)-1;
  }
  __syncthreads();
  {
    const int SCH = 13;
    int base = tid * SCH;
    int lim = base + SCH; if (lim > NA) lim = NA;
    int s = 0;
    for (int j = base; j < lim; j++) s += H[j];
    int run = blockScanEx(s);
    for (int j = base; j < lim; j++) { run += H[j]; H[j] = (short)run; }
  }
  __syncthreads();
  if (tid == 0) { spackU = 0; smaxd = 0; scenter = 0x7FFFFFFF; }
  __syncthreads();
  for (int a = tid; a < NA; a += nt) {
    int pa = NA - 1 - (int)r_a[a];
    int pb = NA - 1 - (int)r_a[a ^ 1];
    if (pa < pb) {
      int e = a >> 1;
      int head = (a & 1) ? mu[e] : mv[e];
      depthR[head] = (unsigned short)H[pa];
      firstK[head] = (unsigned short)(pa + 1);
    }
  }
  if (tid == 0) { depthR[ROOT] = 0; firstK[ROOT] = 0; }
  __syncthreads();
  {
    int loc = 0;
    for (int v = tid; v < VV; v += nt) { int p = ((int)depthR[v] << 13) | v; if (p > loc) loc = p; }
    #pragma unroll
    for (int d = 32; d > 0; d >>= 1) { int o = __shfl_down(loc, d); if (o > loc) loc = o; }
    if (lane == 0) atomicMax(&spackU, loc);
  }
  __syncthreads();
  {
    for (int seg = wid; seg < NB; seg += 16) {
      int p = seg * 64 + lane;
      int h = (p < NA) ? (int)H[p] : 32767;
      int hp = h;
      #pragma unroll
      for (int d = 1; d < 64; d <<= 1) { int o = __shfl_up(hp, d); if (lane >= d && o < hp) hp = o; }
      prefmin[p] = (short)hp;
      int hs = h;
      #pragma unroll
      for (int d = 1; d < 64; d <<= 1) { int o = __shfl_down(hs, d); if (lane + d < 64 && o < hs) hs = o; }
      sufmin[p] = (short)hs;
      if (lane == 0) tbl[seg] = (short)hs;
    }
  }
  __syncthreads();
  for (int k = 1; k < 8; k++) {
    short vv_ = 0;
    if (tid < NB) {
      int o = tid + (1 << (k - 1));
      short a = tbl[(k - 1) * NB + tid];
      short b2 = (o < NB) ? tbl[(k - 1) * NB + o] : (short)32767;
      vv_ = (a < b2) ? a : b2;
    }
    __syncthreads();
    if (tid < NB) tbl[k * NB + tid] = vv_;
    __syncthreads();
  }
  auto distq = [&](int K1, int K2) -> int {
    if (K1 == K2) return 0;
    int l = (K1 < K2 ? K1 : K2) - 1;
    int r = (K1 > K2 ? K1 : K2) - 1;
    int m = 32767;
    int l0 = l < 0 ? 0 : l;
    int bl = l0 >> 6, br = r >> 6;
    if (bl == br) {
      for (int p = l0; p <= r; p++) { int h = H[p]; if (h < m) m = h; }
    } else {
      int a = sufmin[l0], b2 = prefmin[r];
      m = a < b2 ? a : b2;
      int lo = bl + 1, hi = br - 1;
      if (lo <= hi) {
        int L = hi - lo + 1;
        int k = 31 - __builtin_clz(L);
        int c1 = tbl[k * NB + lo];
        int c2 = tbl[k * NB + hi - (1 << k) + 1];
        if (c1 < m) m = c1;
        if (c2 < m) m = c2;
      }
    }
    if (l < 0 && 0 < m) m = 0;
    int h1 = (K1 == 0) ? 0 : (int)H[K1 - 1];
    int h2 = (K2 == 0) ? 0 : (int)H[K2 - 1];
    return h1 + h2 - 2 * m;
  };
  int u = spackU & 0x1FFF;
  int Ku = firstK[u];
  if (tid == 0) spackW = 0;
  __syncthreads();
  {
    int loc = 0;
    for (int v = tid; v < VV; v += nt) {
      int d = distq(Ku, firstK[v]);
      distU[v] = (unsigned short)d;
      int p = (d << 13) | v;
      if (p > loc) loc = p;
    }
    #pragma unroll
    for (int d = 32; d > 0; d >>= 1) { int o = __shfl_down(loc, d); if (o > loc) loc = o; }
    if (lane == 0) atomicMax(&spackW, loc);
  }
  __syncthreads();
  int D = spackW >> 13;
  int w = spackW & 0x1FFF;
  int Kw = firstK[w];
  for (int v = tid; v < VV; v += nt) dbuf2[v] = (unsigned short)distq(Kw, firstK[v]);
  __syncthreads();
  {
    int half = D >> 1;
    for (int v = tid; v < VV; v += nt) {
      if ((int)distU[v] == half && (int)distU[v] + (int)dbuf2[v] == D) atomicMin(&scenter, v);
    }
  }
  __syncthreads();
  int cvert = (scenter == 0x7FFFFFFF) ? ROOT : scenter;
  int Kc = firstK[cvert];
  __syncthreads();
  {
    int loc = 0;
    for (int v = tid; v < VV; v += nt) {
      int d = distq(Kc, firstK[v]);
      dbuf2[v] = (unsigned short)d;
      if (d > loc) loc = d;
    }
    #pragma unroll
    for (int d = 32; d > 0; d >>= 1) { int o = __shfl_down(loc, d); if (o > loc) loc = o; }
    if (lane == 0) atomicMax(&smaxd, loc);
  }
  __syncthreads();
  int maxd = smaxd;
  int sTil = Kc;
  for (int a = tid; a < NA; a += nt) {
    int pa = NA - 1 - (int)r_a[a];
    int pb = NA - 1 - (int)r_a[a ^ 1];
    int pa2 = pa - sTil; if (pa2 < 0) pa2 += NA;
    int pb2 = pb - sTil; if (pb2 < 0) pb2 += NA;
    if (pa2 < pb2) {
      int e = a >> 1;
      int head = (a & 1) ? mu[e] : mv[e];
      int tail = (a & 1) ? mv[e] : mu[e];
      parentS[head] = (unsigned short)tail;
    }
  }
  if (tid == 0) parentS[cvert] = (unsigned short)cvert;
  __syncthreads();
  for (int d = tid; d <= VV; d += nt) lev[d] = 0;
  __syncthreads();
  for (int v = tid; v < VV; v += nt) atomicAdd(&lev[dbuf2[v]], 1);
  __syncthreads();
  {
    const int SCH = 7;
    int base = tid * SCH;
    int s = 0;
    #pragma unroll
    for (int k = 0; k < SCH; k++) { int d = base + k; if (d <= VV) s += lev[d]; }
    int ex = blockScanEx(s);
    #pragma unroll
    for (int k = 0; k < SCH; k++) {
      int d = base + k;
      if (d <= VV) {
        int st = ex;
        ex += lev[d];
        if (d < VV) cur[d] = st;
        lpG[t * (VV + 1) + d] = st;
      }
    }
  }
  __syncthreads();
  for (int v = tid; v < VV; v += nt) {
    int d = dbuf2[v];
    int slot = atomicAdd(&cur[d], 1);
    ordS[slot] = (unsigned short)v;
    posS[v] = (unsigned short)slot;
  }
  __syncthreads();
  for (int j = tid; j < VV; j += nt) {
    int v = ordS[j];
    int pv = parentS[v];
    ordG[t * VV + j] = v;
    spG[t * VV + j] = posS[pv];
    float wout;
    if (v == pv) {
      wout = 1.0f;  // root (filter transform special-cases pos 0)
    } else {
      int a = v < pv ? v : pv;
      int diff = v < pv ? pv - v : v - pv;
      int e;
      if (diff == WW) e = a;
      else { int r = a / WW, c = a - r * WW; e = EVERT + r * (WW - 1) + c; }
      unsigned long long k = key[e];
      double cost = __longlong_as_double((long long)(k & ~0x3FFFULL));
      wout = expf(-(float)cost / SIGMA_F);
    }
    wvp[t * VV + j] = wout;
  }
  if (tid == 0) nlevG[t] = maxd + 1;
}

// ---------------- K6: tree filter — 1024 threads; level-sweep up (wave 0), float2 doubling down ----------------
__global__ __launch_bounds__(1024) void k_filter_pc(const float* __restrict__ Fsrc, float* __restrict__ Araw,
    const float* __restrict__ wvp, const int* __restrict__ ordG, const int* __restrict__ spG,
    const int* __restrict__ lpG, const int* __restrict__ nlevG, int treeBase) {
  int blk = blockIdx.x;
  int b = blk / CF, ch = blk - b * CF;
  int t = treeBase + b;
  __shared__ alignas(16) char arena[140816];
  float2* ab0 = (float2*)(arena);
  float2* ab1 = (float2*)(arena + 51200);
  float*  S   = (float*)(arena + 51200);
  float*  w   = (float*)(arena + 76800);
  unsigned short* sp0 = (unsigned short*)(arena + 102400);
  unsigned short* sp1 = (unsigned short*)(arena + 115200);
  unsigned short* lpS = (unsigned short*)(arena + 128000);
  const int* ord = ordG + t * VV;
  const int* spt = spG + t * VV;
  const float* wsrc = wvp + t * VV;
  const int* lp = lpG + t * (VV + 1);
  int tid = threadIdx.x;
  const int nt = 1024;
  int NL = nlevG[t];
  for (int j = tid; j <= NL; j += nt) lpS[j] = (unsigned short)lp[j];
  const bool norm_in = (treeBase != 0);
  for (int j = tid; j < VV; j += nt) {
    sp0[j] = (unsigned short)spt[j];
    w[j] = wsrc[j];
    float val;
    if (ch < CP) {
      int v = ord[j];
      if (!norm_in) val = Fsrc[((size_t)b * CP + ch) * VV + v];
      else          val = Fsrc[((size_t)b * CF + ch) * VV + v] / Fsrc[((size_t)b * CF + CP) * VV + v];
    } else val = 1.0f;
    S[j] = val;
  }
  __syncthreads();
  if (tid < 64) {
    int s1 = lpS[NL];
    int s0 = lpS[NL - 1];
    for (int l = NL - 1; l >= 1; l--) {
      int s0n = (l > 1) ? (int)lpS[l - 1] : 0;
      for (int j = s0 + tid; j < s1; j += 64) {
        atomicAdd(&S[sp0[j]], w[j] * S[j]);
      }
      asm volatile("s_waitcnt lgkmcnt(0)" ::: "memory");
      __builtin_amdgcn_sched_barrier(0);
      s1 = s0; s0 = s0n;
    }
  }
  __syncthreads();
  for (int j = tid; j < VV; j += nt) {
    float wv = w[j];
    float a = (j == 0) ? 0.f : wv;
    float bv = (j == 0) ? S[0] : S[j] * (1.f - wv * wv);
    ab0[j] = make_float2(a, bv);
  }
  __syncthreads();
  int rounds = 0;
  { int d = 1; while (d < NL) { d <<= 1; rounds++; } }
  float2 *abs_ = ab0, *abd_ = ab1;
  unsigned short *ps_ = sp0, *pd_ = sp1;
  for (int r = 0; r < rounds; r++) {
    for (int j = tid; j < VV; j += nt) {
      float2 m = abs_[j];
      int p = ps_[j];
      float2 o = m;
      int pn = p;
      if (m.x != 0.f) {
        float2 mp = abs_[p];
        pn = ps_[p];
        o.x = m.x * mp.x;
        o.y = fmaf(m.x, mp.y, m.y);
      }
      abd_[j] = o;
      pd_[j] = (unsigned short)pn;
    }
    __syncthreads();
    float2* tf = abs_; abs_ = abd_; abd_ = tf;
    unsigned short* tu = ps_; ps_ = pd_; pd_ = tu;
  }
  float* Ob = Araw + ((size_t)b * CF + ch) * VV;
  for (int j = tid; j < VV; j += nt) Ob[ord[j]] = abs_[j].y;
}

// ---------------- K7: ROI-masked L1 loss with fused finalize (last-block-done) ----------------
__global__ void k_loss(const float* __restrict__ prob, const float* __restrict__ Araw2,
                       const int* __restrict__ roi, double* __restrict__ acc,
                       unsigned int* __restrict__ done, float* __restrict__ out) {
  int i = blockIdx.x * blockDim.x + threadIdx.x;
  int tid = threadIdx.x;
  double s = 0.0, n = 0.0;
  if (i < BB * VV) {
    int b = i / VV, v = i - b * VV;
    if (roi[i] != 0) {
      n = 1.0;
      const float* pb = prob + (size_t)b * CP * VV + v;
      const float* ab = Araw2 + (size_t)b * CF * VV + v;
      float inv = 1.0f / ab[CP * VV];
      float ls = 0.f;
      #pragma unroll
      for (int c = 0; c < CP; c++) ls += fabsf(pb[c * VV] - ab[c * VV] * inv);
      s = (double)ls;
    }
  }
  __shared__ double rs[256], rn[256];
  __shared__ bool amLast;
  rs[tid] = s; rn[tid] = n;
  __syncthreads();
  for (int d = 128; d > 0; d >>= 1) {
    if (tid < d) { rs[tid] += rs[tid + d]; rn[tid] += rn[tid + d]; }
    __syncthreads();
  }
  if (tid == 0) {
    atomicAdd(&acc[0], rs[0]);
    atomicAdd(&acc[1], rn[0]);
    __threadfence();
    unsigned int prev = atomicAdd(done, 1u);
    amLast = (prev == gridDim.x - 1);
  }
  __syncthreads();
  if (amLast && tid == 0) {
    __threadfence();
    double ss = acc[0], nn = acc[1];
    out[0] = (nn > 0.0) ? (float)(ss / nn) : 0.0f;
  }
}

extern "C" void kernel_launch(void* const* d_in, const int* in_sizes, int n_in,
                              void* d_out, int out_size, void* d_ws, size_t ws_size,
                              hipStream_t stream) {
  const float* preds = (const float*)d_in[0];
  const float* low   = (const float*)d_in[1];
  const float* high  = (const float*)d_in[2];
  const int*   roi   = (const int*)d_in[3];
  float* out = (float*)d_out;

  char* w = (char*)d_ws;
  size_t off = 0;
  auto alloc = [&](size_t bytes) -> void* {
    void* p = w + off;
    off += (bytes + 255) & ~(size_t)255;
    return p;
  };
  float* prob  = (float*)alloc((size_t)BB * CP * VV * 4);
  float* Araw1 = (float*)alloc((size_t)BB * CF * VV * 4);
  float* Araw2 = (float*)alloc((size_t)BB * CF * VV * 4);
  unsigned long long* ekey = (unsigned long long*)alloc((size_t)TT * EE * 8);
  int* mstU = (int*)alloc((size_t)TT * VV * 4);
  int* mstV = (int*)alloc((size_t)TT * VV * 4);
  int* ordG = (int*)alloc((size_t)TT * VV * 4);
  int* spG  = (int*)alloc((size_t)TT * VV * 4);
  int* lpG  = (int*)alloc((size_t)TT * (VV + 1) * 4);
  int* nlev = (int*)alloc((size_t)TT * 4);
  float* wvp = (float*)alloc((size_t)TT * VV * 4);
  double* acc = (double*)alloc(32);

  hipMemsetAsync(acc, 0, 32, stream);   // zeroes acc[0..1] and the done counter

  const int nSoft = (BB * VV + 1023) / 1024;   // 50 softmax side-car blocks
  k_edgekey<<<(TT * EE + 255) / 256, 256, 0, stream>>>(low, high, ekey);
  k_msttree<<<TT + nSoft, 1024, 0, stream>>>(ekey, mstU, mstV, ordG, spG, lpG, nlev, wvp, preds, prob);
  k_filter_pc<<<BB * CF, 1024, 0, stream>>>(prob,  Araw1, wvp, ordG, spG, lpG, nlev, 0);
  k_filter_pc<<<BB * CF, 1024, 0, stream>>>(Araw1, Araw2, wvp, ordG, spG, lpG, nlev, BB);
  k_loss<<<(BB * VV + 255) / 256, 256, 0, stream>>>(prob, Araw2, roi, acc,
      (unsigned int*)(acc + 2), out);
}